// Round 1
// baseline (2997.928 us; speedup 1.0000x reference)
//
#include <hip/hip_runtime.h>
#include <math.h>

// Problem constants
#define BB 2
#define TT 2048
#define CC 2048
#define HH 16
#define HKK 4
#define HD 128
#define MM (BB*TT)          // 4096 rows
// GEMM tiling
#define Bb_M 64
#define Bb_N 64
#define Bb_K 16

// ---------------------------------------------------------------------------
// Fused QKV projection: [4096 x 2048] @ [2048 x 3072] (Wq|Wk|Wv) + bias
// Each 64-wide column block lies entirely in one region (2048, 2560 are x64).
// ---------------------------------------------------------------------------
__global__ __launch_bounds__(256) void qkv_gemm(
    const float* __restrict__ x,
    const float* __restrict__ Wq, const float* __restrict__ bq,
    const float* __restrict__ Wk, const float* __restrict__ bk,
    const float* __restrict__ Wv, const float* __restrict__ bv,
    float* __restrict__ q, float* __restrict__ k, float* __restrict__ v)
{
    __shared__ float As[Bb_K][Bb_M];      // [k][m]
    __shared__ float Bs[Bb_K][Bb_N];      // [k][n]

    const int tid = threadIdx.x;
    const int tx = tid & 15;              // 0..15 -> 4 cols each
    const int ty = tid >> 4;              // 0..15 -> 4 rows each
    const int m0 = blockIdx.y * Bb_M;
    const int n0 = blockIdx.x * Bb_N;

    const float* W; const float* bias; float* dst; int ldW, ldD, off;
    if (n0 < 2048)      { W = Wq; bias = bq; dst = q; ldW = 2048; ldD = 2048; off = n0; }
    else if (n0 < 2560) { W = Wk; bias = bk; dst = k; ldW = 512;  ldD = 512;  off = n0 - 2048; }
    else                { W = Wv; bias = bv; dst = v; ldW = 512;  ldD = 512;  off = n0 - 2560; }

    // staging indices
    const int arow = tid >> 2;            // 0..63 (m_local)
    const int acol = (tid & 3) * 4;       // k_local (float4)
    const int brow = tid >> 4;            // 0..15  (k_local)
    const int bcol = (tid & 15) * 4;      // n_local (float4)

    float acc[4][4] = {};

    for (int kt = 0; kt < CC; kt += Bb_K) {
        float4 a4 = *(const float4*)&x[(m0 + arow) * CC + kt + acol];
        float4 b4 = *(const float4*)&W[(kt + brow) * ldW + off + bcol];
        __syncthreads();
        As[acol + 0][arow] = a4.x;
        As[acol + 1][arow] = a4.y;
        As[acol + 2][arow] = a4.z;
        As[acol + 3][arow] = a4.w;
        *(float4*)&Bs[brow][bcol] = b4;
        __syncthreads();
#pragma unroll
        for (int kk = 0; kk < Bb_K; ++kk) {
            float4 av = *(const float4*)&As[kk][ty * 4];
            float4 bv4 = *(const float4*)&Bs[kk][tx * 4];
            acc[0][0] += av.x * bv4.x; acc[0][1] += av.x * bv4.y;
            acc[0][2] += av.x * bv4.z; acc[0][3] += av.x * bv4.w;
            acc[1][0] += av.y * bv4.x; acc[1][1] += av.y * bv4.y;
            acc[1][2] += av.y * bv4.z; acc[1][3] += av.y * bv4.w;
            acc[2][0] += av.z * bv4.x; acc[2][1] += av.z * bv4.y;
            acc[2][2] += av.z * bv4.z; acc[2][3] += av.z * bv4.w;
            acc[3][0] += av.w * bv4.x; acc[3][1] += av.w * bv4.y;
            acc[3][2] += av.w * bv4.z; acc[3][3] += av.w * bv4.w;
        }
    }

    float bx0 = bias[off + tx * 4 + 0];
    float bx1 = bias[off + tx * 4 + 1];
    float bx2 = bias[off + tx * 4 + 2];
    float bx3 = bias[off + tx * 4 + 3];
#pragma unroll
    for (int i = 0; i < 4; ++i) {
        float4 r;
        r.x = acc[i][0] + bx0;
        r.y = acc[i][1] + bx1;
        r.z = acc[i][2] + bx2;
        r.w = acc[i][3] + bx3;
        *(float4*)&dst[(m0 + ty * 4 + i) * ldD + off + tx * 4] = r;
    }
}

// ---------------------------------------------------------------------------
// Plain GEMM: out[4096x2048] = y[4096x2048] @ Wo[2048x2048]
// ---------------------------------------------------------------------------
__global__ __launch_bounds__(256) void out_gemm(
    const float* __restrict__ A, const float* __restrict__ B,
    float* __restrict__ Cout)
{
    __shared__ float As[Bb_K][Bb_M];
    __shared__ float Bs[Bb_K][Bb_N];

    const int tid = threadIdx.x;
    const int tx = tid & 15;
    const int ty = tid >> 4;
    const int m0 = blockIdx.y * Bb_M;
    const int n0 = blockIdx.x * Bb_N;

    const int arow = tid >> 2;
    const int acol = (tid & 3) * 4;
    const int brow = tid >> 4;
    const int bcol = (tid & 15) * 4;

    float acc[4][4] = {};

    for (int kt = 0; kt < CC; kt += Bb_K) {
        float4 a4 = *(const float4*)&A[(m0 + arow) * CC + kt + acol];
        float4 b4 = *(const float4*)&B[(kt + brow) * CC + n0 + bcol];
        __syncthreads();
        As[acol + 0][arow] = a4.x;
        As[acol + 1][arow] = a4.y;
        As[acol + 2][arow] = a4.z;
        As[acol + 3][arow] = a4.w;
        *(float4*)&Bs[brow][bcol] = b4;
        __syncthreads();
#pragma unroll
        for (int kk = 0; kk < Bb_K; ++kk) {
            float4 av = *(const float4*)&As[kk][ty * 4];
            float4 bv4 = *(const float4*)&Bs[kk][tx * 4];
            acc[0][0] += av.x * bv4.x; acc[0][1] += av.x * bv4.y;
            acc[0][2] += av.x * bv4.z; acc[0][3] += av.x * bv4.w;
            acc[1][0] += av.y * bv4.x; acc[1][1] += av.y * bv4.y;
            acc[1][2] += av.y * bv4.z; acc[1][3] += av.y * bv4.w;
            acc[2][0] += av.z * bv4.x; acc[2][1] += av.z * bv4.y;
            acc[2][2] += av.z * bv4.z; acc[2][3] += av.z * bv4.w;
            acc[3][0] += av.w * bv4.x; acc[3][1] += av.w * bv4.y;
            acc[3][2] += av.w * bv4.z; acc[3][3] += av.w * bv4.w;
        }
    }

#pragma unroll
    for (int i = 0; i < 4; ++i) {
        float4 r;
        r.x = acc[i][0]; r.y = acc[i][1]; r.z = acc[i][2]; r.w = acc[i][3];
        *(float4*)&Cout[(m0 + ty * 4 + i) * CC + n0 + tx * 4] = r;
    }
}

// ---------------------------------------------------------------------------
// RoPE applied in place to q (16 heads) and k (4 heads).
// rotate_half: out[d]    = t[d]*cos[d]    - t[d+64]*sin[d]
//              out[d+64] = t[d+64]*cos[d+64] + t[d]*sin[d+64]
// ---------------------------------------------------------------------------
__global__ __launch_bounds__(256) void rope_kernel(
    float* __restrict__ q, float* __restrict__ k,
    const float* __restrict__ cosb, const float* __restrict__ sinb)
{
    int slot = blockIdx.x * 4 + (threadIdx.x >> 6);  // 0 .. B*T*20-1
    int d = threadIdx.x & 63;
    int row = slot / 20;        // b*T + t
    int s = slot - row * 20;    // head slot: 0..15 q, 16..19 k
    float* p = (s < 16) ? (q + (size_t)row * CC + s * HD)
                        : (k + (size_t)row * (HKK * HD) + (s - 16) * HD);
    float c1 = cosb[row * HD + d];
    float s1 = sinb[row * HD + d];
    float c2 = cosb[row * HD + 64 + d];
    float s2 = sinb[row * HD + 64 + d];
    float x1 = p[d];
    float x2 = p[d + 64];
    p[d]      = x1 * c1 - x2 * s1;
    p[d + 64] = x2 * c2 + x1 * s2;
}

// ---------------------------------------------------------------------------
// Causal flash attention, f32. Block: 256 threads, BR=BC=32 tile, D=128.
// Thread t owns score/O row r=t>>3; seg=t&7.
// Score cols: seg + 8*jj (jj=0..3)  -> conflict-free Ks reads (stride 132).
// O cols: seg*4 + 32*m + i (m=0..3) -> conflict-free Vs reads.
// Per-row softmax state (m_i, l_i) kept redundantly in the 8 owning lanes
// (butterfly shuffle over lanes xor 1,2,4 stays inside the row group).
// ---------------------------------------------------------------------------
#define LDP 132   // padded LDS row stride (floats): 132%32=4 -> row-major b128 conflict-free

__global__ __launch_bounds__(256) void flash_kernel(
    const float* __restrict__ q, const float* __restrict__ k,
    const float* __restrict__ v, float* __restrict__ y)
{
    __shared__ float Qs[32][LDP];
    __shared__ float Ks[32][LDP];
    __shared__ float Vs[32][LDP];
    __shared__ float Ss[32][33];

    const int tid = threadIdx.x;
    const int qi = blockIdx.x;            // q tile index (0..63)
    const int bh = blockIdx.y;            // 0..31
    const int b = bh >> 4, h = bh & 15, g = h >> 2;
    const int q0 = qi * 32;
    const float scale = 0.08838834764831845f;  // 1/sqrt(128)

    // load Q tile (32 x 128)
    {
        int r = tid >> 5;                 // 0..7
        int c = (tid & 31) * 4;
#pragma unroll
        for (int i = 0; i < 4; ++i) {
            int rr = r + i * 8;
            *(float4*)&Qs[rr][c] =
                *(const float4*)&q[(size_t)(b * TT + q0 + rr) * CC + h * HD + c];
        }
    }

    const int row = tid >> 3;             // 0..31
    const int seg = tid & 7;              // 0..7
    float m_i = -1e30f, l_i = 0.0f;
    float acc[4][4];                      // [chunk m][i] -> col seg*4 + 32*m + i
#pragma unroll
    for (int m = 0; m < 4; ++m)
#pragma unroll
        for (int i = 0; i < 4; ++i) acc[m][i] = 0.0f;

    for (int j = 0; j <= qi; ++j) {
        __syncthreads();   // prev iteration's PV reads complete before overwrite
        {
            int r = tid >> 5;
            int c = (tid & 31) * 4;
#pragma unroll
            for (int i = 0; i < 4; ++i) {
                int rr = r + i * 8;
                size_t base = (size_t)(b * TT + j * 32 + rr) * (HKK * HD) + g * HD + c;
                *(float4*)&Ks[rr][c] = *(const float4*)&k[base];
                *(float4*)&Vs[rr][c] = *(const float4*)&v[base];
            }
        }
        __syncthreads();

        // scores: 4 per thread at cols seg + 8*jj
        float s[4] = {0.f, 0.f, 0.f, 0.f};
        for (int d = 0; d < HD; d += 4) {
            float4 qv = *(const float4*)&Qs[row][d];
#pragma unroll
            for (int jj = 0; jj < 4; ++jj) {
                float4 kv = *(const float4*)&Ks[seg + jj * 8][d];
                s[jj] += qv.x * kv.x + qv.y * kv.y + qv.z * kv.z + qv.w * kv.w;
            }
        }
        float tmax = -1e30f;
#pragma unroll
        for (int jj = 0; jj < 4; ++jj) {
            int c = seg + jj * 8;
            s[jj] *= scale;
            if (j == qi && (j * 32 + c) > (q0 + row)) s[jj] = -1e30f;
            tmax = fmaxf(tmax, s[jj]);
        }
        // reduce max over the 8 lanes of this row (lanes differ in low 3 bits)
        for (int o = 1; o < 8; o <<= 1) tmax = fmaxf(tmax, __shfl_xor(tmax, o));
        float m_new = fmaxf(m_i, tmax);
        float alpha = __expf(m_i - m_new);

        float psum = 0.0f;
#pragma unroll
        for (int jj = 0; jj < 4; ++jj) {
            float p = __expf(s[jj] - m_new);
            psum += p;
            Ss[row][seg + jj * 8] = p;
        }
        for (int o = 1; o < 8; o <<= 1) psum += __shfl_xor(psum, o);
        l_i = l_i * alpha + psum;
        m_i = m_new;
        __syncthreads();   // Ss/Vs ready for all rows

        // O = O*alpha + P @ V
#pragma unroll
        for (int m = 0; m < 4; ++m)
#pragma unroll
            for (int i = 0; i < 4; ++i) acc[m][i] *= alpha;

        for (int c = 0; c < 32; ++c) {
            float pc = Ss[row][c];
#pragma unroll
            for (int m = 0; m < 4; ++m) {
                float4 vv = *(const float4*)&Vs[c][seg * 4 + 32 * m];
                acc[m][0] += pc * vv.x;
                acc[m][1] += pc * vv.y;
                acc[m][2] += pc * vv.z;
                acc[m][3] += pc * vv.w;
            }
        }
    }

    // epilogue: y[b, q0+row, h*128 + col] = acc/l
    float inv = 1.0f / l_i;
    size_t base = (size_t)(b * TT + q0 + row) * CC + h * HD;
#pragma unroll
    for (int m = 0; m < 4; ++m) {
        float4 o4;
        o4.x = acc[m][0] * inv;
        o4.y = acc[m][1] * inv;
        o4.z = acc[m][2] * inv;
        o4.w = acc[m][3] * inv;
        *(float4*)&y[base + seg * 4 + 32 * m] = o4;
    }
}

// ---------------------------------------------------------------------------
extern "C" void kernel_launch(void* const* d_in, const int* in_sizes, int n_in,
                              void* d_out, int out_size, void* d_ws, size_t ws_size,
                              hipStream_t stream) {
    const float* x    = (const float*)d_in[0];
    const float* cosb = (const float*)d_in[1];
    const float* sinb = (const float*)d_in[2];
    const float* Wq   = (const float*)d_in[3];
    const float* bq   = (const float*)d_in[4];
    const float* Wk   = (const float*)d_in[5];
    const float* bk   = (const float*)d_in[6];
    const float* Wv   = (const float*)d_in[7];
    const float* bv   = (const float*)d_in[8];
    const float* Wo   = (const float*)d_in[9];
    float* out = (float*)d_out;

    // workspace layout (f32): q[4096*2048] | k[4096*512] | v[4096*512] | y[4096*2048]
    float* qb = (float*)d_ws;
    float* kb = qb + (size_t)MM * CC;
    float* vb = kb + (size_t)MM * (HKK * HD);
    float* yb = vb + (size_t)MM * (HKK * HD);

    // QKV projection + bias: N = 2048 + 512 + 512 = 3072 -> 48 col blocks
    qkv_gemm<<<dim3(48, MM / Bb_M), 256, 0, stream>>>(x, Wq, bq, Wk, bk, Wv, bv, qb, kb, vb);

    // RoPE in place on q (16 heads) and k (4 heads): B*T*20 slots, 4 per block
    rope_kernel<<<dim3((MM * 20) / 4), 256, 0, stream>>>(qb, kb, cosb, sinb);

    // causal flash attention -> y
    flash_kernel<<<dim3(TT / 32, BB * HH), 256, 0, stream>>>(qb, kb, vb, yb);

    // output projection
    out_gemm<<<dim3(CC / Bb_N, MM / Bb_M), 256, 0, stream>>>(yb, Wo, out);
}

// Round 3
// 562.312 us; speedup vs baseline: 5.3314x; 5.3314x over previous
//
#include <hip/hip_runtime.h>
#include <math.h>

// Problem constants
#define BB 2
#define TT 2048
#define CC 2048
#define HH 16
#define HKK 4
#define HD 128
#define MM (BB*TT)          // 4096 rows

typedef short bf16x8 __attribute__((ext_vector_type(8)));
typedef float f32x4 __attribute__((ext_vector_type(4)));

__device__ __forceinline__ unsigned short f2bf(float f) {
    unsigned u = __float_as_uint(f);
    u += 0x7fff + ((u >> 16) & 1);          // round-to-nearest-even
    return (unsigned short)(u >> 16);
}
__device__ __forceinline__ float bf2f(unsigned short h) {
    return __uint_as_float(((unsigned)h) << 16);
}

// ---------------------------------------------------------------------------
// cast x (f32 -> bf16), 8 elements/thread
// ---------------------------------------------------------------------------
__global__ __launch_bounds__(256) void cast_x_kernel(
    const float* __restrict__ x, unsigned short* __restrict__ xb)
{
    size_t i = ((size_t)blockIdx.x * 256 + threadIdx.x) * 8;
    float4 a = *(const float4*)&x[i];
    float4 b = *(const float4*)&x[i + 4];
    uint4 r;
    r.x = f2bf(a.x) | ((unsigned)f2bf(a.y) << 16);
    r.y = f2bf(a.z) | ((unsigned)f2bf(a.w) << 16);
    r.z = f2bf(b.x) | ((unsigned)f2bf(b.y) << 16);
    r.w = f2bf(b.z) | ((unsigned)f2bf(b.w) << 16);
    *(uint4*)&xb[i] = r;
}

// ---------------------------------------------------------------------------
// Weight transpose+cast: W[K][N] f32 -> Wt[N][K] bf16.
// z=0 Wq->Wt rows 0..2047, z=1 Wk->Wt rows 2048..2559, z=2 Wv->Wt 2560..3071,
// z=3 Wo->Wot rows 0..2047.  All have K=2048.
// ---------------------------------------------------------------------------
__global__ __launch_bounds__(256) void wtrans_kernel(
    const float* __restrict__ Wq, const float* __restrict__ Wk,
    const float* __restrict__ Wv, const float* __restrict__ Wo,
    unsigned short* __restrict__ Wt, unsigned short* __restrict__ Wot)
{
    __shared__ float tile[64][65];
    int z = blockIdx.z;
    const float* src; unsigned short* dst; int ldW, nmax, noff;
    if (z == 0)      { src = Wq; dst = Wt;  ldW = 2048; nmax = 2048; noff = 0; }
    else if (z == 1) { src = Wk; dst = Wt;  ldW = 512;  nmax = 512;  noff = 2048; }
    else if (z == 2) { src = Wv; dst = Wt;  ldW = 512;  nmax = 512;  noff = 2560; }
    else             { src = Wo; dst = Wot; ldW = 2048; nmax = 2048; noff = 0; }
    int n0 = blockIdx.y * 64;
    if (n0 >= nmax) return;
    int k0 = blockIdx.x * 64;
    int tx = threadIdx.x & 15, ty = threadIdx.x >> 4;
#pragma unroll
    for (int i = 0; i < 4; ++i) {
        int r = ty + i * 16;
        float4 v4 = *(const float4*)&src[(size_t)(k0 + r) * ldW + n0 + tx * 4];
        tile[r][tx * 4 + 0] = v4.x;
        tile[r][tx * 4 + 1] = v4.y;
        tile[r][tx * 4 + 2] = v4.z;
        tile[r][tx * 4 + 3] = v4.w;
    }
    __syncthreads();
#pragma unroll
    for (int i = 0; i < 4; ++i) {
        int r = ty + i * 16;     // n-local
        int c = tx * 4;          // k-local
        ushort4 o;
        o.x = f2bf(tile[c + 0][r]);
        o.y = f2bf(tile[c + 1][r]);
        o.z = f2bf(tile[c + 2][r]);
        o.w = f2bf(tile[c + 3][r]);
        *(ushort4*)&dst[(size_t)(noff + n0 + r) * 2048 + k0 + c] = o;
    }
}

// ---------------------------------------------------------------------------
// MFMA GEMM 128x128x32 tile, 4 waves (2x2), 16x16x32 bf16, single-buffered.
// A: xb[M=4096][K=2048] bf16.  B: Wt[N][K] bf16 (pre-transposed).
// ---------------------------------------------------------------------------
__global__ __launch_bounds__(256) void qkv_gemm_mfma(
    const unsigned short* __restrict__ xb, const unsigned short* __restrict__ Wt,
    const float* __restrict__ bq, const float* __restrict__ bk, const float* __restrict__ bv,
    unsigned short* __restrict__ q, unsigned short* __restrict__ k, unsigned short* __restrict__ v)
{
    __shared__ __attribute__((aligned(16))) short As[128 * 32];
    __shared__ __attribute__((aligned(16))) short Bs[128 * 32];
    const int tid = threadIdx.x;
    const int lane = tid & 63;
    const int w = tid >> 6;
    const int wm = (w & 1) * 64;
    const int wn = (w >> 1) * 64;
    const int m0 = blockIdx.y * 128;
    const int n0 = blockIdx.x * 128;
    const int lm = lane & 15;
    const int q8 = lane >> 4;

    f32x4 acc[4][4];
#pragma unroll
    for (int im = 0; im < 4; ++im)
#pragma unroll
        for (int in = 0; in < 4; ++in) acc[im][in] = {0.f, 0.f, 0.f, 0.f};

    const int srow = tid >> 2;          // 0..63
    const int sk8 = (tid & 3) * 8;      // k chunk offset (bf16)

    for (int kt = 0; kt < CC; kt += 32) {
        uint4 a0 = *(const uint4*)&xb[(size_t)(m0 + srow) * CC + kt + sk8];
        uint4 a1 = *(const uint4*)&xb[(size_t)(m0 + 64 + srow) * CC + kt + sk8];
        uint4 b0 = *(const uint4*)&Wt[(size_t)(n0 + srow) * CC + kt + sk8];
        uint4 b1 = *(const uint4*)&Wt[(size_t)(n0 + 64 + srow) * CC + kt + sk8];
        __syncthreads();
        ((uint4*)As)[tid] = a0;
        ((uint4*)As)[tid + 256] = a1;
        ((uint4*)Bs)[tid] = b0;
        ((uint4*)Bs)[tid + 256] = b1;
        __syncthreads();
        bf16x8 af[4], bf[4];
#pragma unroll
        for (int i = 0; i < 4; ++i) {
            af[i] = *(const bf16x8*)&As[(wm + i * 16 + lm) * 32 + q8 * 8];
            bf[i] = *(const bf16x8*)&Bs[(wn + i * 16 + lm) * 32 + q8 * 8];
        }
#pragma unroll
        for (int im = 0; im < 4; ++im)
#pragma unroll
            for (int in = 0; in < 4; ++in)
                acc[im][in] = __builtin_amdgcn_mfma_f32_16x16x32_bf16(af[im], bf[in], acc[im][in], 0, 0, 0);
    }

    unsigned short* dst; const float* bias; int ldD, off;
    if (n0 < 2048)      { dst = q; bias = bq; ldD = 2048; off = n0; }
    else if (n0 < 2560) { dst = k; bias = bk; ldD = 512;  off = n0 - 2048; }
    else                { dst = v; bias = bv; ldD = 512;  off = n0 - 2560; }

#pragma unroll
    for (int in = 0; in < 4; ++in) {
        float bias_v = bias[off + wn + in * 16 + lm];
#pragma unroll
        for (int im = 0; im < 4; ++im) {
#pragma unroll
            for (int r = 0; r < 4; ++r) {
                int row = m0 + wm + im * 16 + q8 * 4 + r;   // C/D: row = quad*4+reg
                dst[(size_t)row * ldD + off + wn + in * 16 + lm] = f2bf(acc[im][in][r] + bias_v);
            }
        }
    }
}

__global__ __launch_bounds__(256) void out_gemm_mfma(
    const unsigned short* __restrict__ yb, const unsigned short* __restrict__ Wot,
    float* __restrict__ Cout)
{
    __shared__ __attribute__((aligned(16))) short As[128 * 32];
    __shared__ __attribute__((aligned(16))) short Bs[128 * 32];
    const int tid = threadIdx.x;
    const int lane = tid & 63;
    const int w = tid >> 6;
    const int wm = (w & 1) * 64;
    const int wn = (w >> 1) * 64;
    const int m0 = blockIdx.y * 128;
    const int n0 = blockIdx.x * 128;
    const int lm = lane & 15;
    const int q8 = lane >> 4;

    f32x4 acc[4][4];
#pragma unroll
    for (int im = 0; im < 4; ++im)
#pragma unroll
        for (int in = 0; in < 4; ++in) acc[im][in] = {0.f, 0.f, 0.f, 0.f};

    const int srow = tid >> 2;
    const int sk8 = (tid & 3) * 8;

    for (int kt = 0; kt < CC; kt += 32) {
        uint4 a0 = *(const uint4*)&yb[(size_t)(m0 + srow) * CC + kt + sk8];
        uint4 a1 = *(const uint4*)&yb[(size_t)(m0 + 64 + srow) * CC + kt + sk8];
        uint4 b0 = *(const uint4*)&Wot[(size_t)(n0 + srow) * CC + kt + sk8];
        uint4 b1 = *(const uint4*)&Wot[(size_t)(n0 + 64 + srow) * CC + kt + sk8];
        __syncthreads();
        ((uint4*)As)[tid] = a0;
        ((uint4*)As)[tid + 256] = a1;
        ((uint4*)Bs)[tid] = b0;
        ((uint4*)Bs)[tid + 256] = b1;
        __syncthreads();
        bf16x8 af[4], bf[4];
#pragma unroll
        for (int i = 0; i < 4; ++i) {
            af[i] = *(const bf16x8*)&As[(wm + i * 16 + lm) * 32 + q8 * 8];
            bf[i] = *(const bf16x8*)&Bs[(wn + i * 16 + lm) * 32 + q8 * 8];
        }
#pragma unroll
        for (int im = 0; im < 4; ++im)
#pragma unroll
            for (int in = 0; in < 4; ++in)
                acc[im][in] = __builtin_amdgcn_mfma_f32_16x16x32_bf16(af[im], bf[in], acc[im][in], 0, 0, 0);
    }

#pragma unroll
    for (int im = 0; im < 4; ++im)
#pragma unroll
        for (int in = 0; in < 4; ++in)
#pragma unroll
            for (int r = 0; r < 4; ++r) {
                int row = m0 + wm + im * 16 + q8 * 4 + r;
                Cout[(size_t)row * CC + n0 + wn + in * 16 + lm] = acc[im][in][r];
            }
}

// ---------------------------------------------------------------------------
// RoPE in place on bf16 q (16 heads) and k (4 heads).
// ---------------------------------------------------------------------------
__global__ __launch_bounds__(256) void rope_bf(
    unsigned short* __restrict__ q, unsigned short* __restrict__ k,
    const float* __restrict__ cosb, const float* __restrict__ sinb)
{
    int slot = blockIdx.x * 4 + (threadIdx.x >> 6);  // 0 .. MM*20-1
    int d = threadIdx.x & 63;
    int row = slot / 20;
    int s = slot - row * 20;
    unsigned short* p = (s < 16) ? (q + (size_t)row * CC + s * HD)
                                 : (k + (size_t)row * (HKK * HD) + (s - 16) * HD);
    float c1 = cosb[row * HD + d],      s1 = sinb[row * HD + d];
    float c2 = cosb[row * HD + 64 + d], s2 = sinb[row * HD + 64 + d];
    float x1 = bf2f(p[d]);
    float x2 = bf2f(p[d + 64]);
    p[d]      = f2bf(x1 * c1 - x2 * s1);
    p[d + 64] = f2bf(x2 * c2 + x1 * s2);
}

// ---------------------------------------------------------------------------
// V transpose: v[b][t][g*128+d] bf16 -> vt[(b*4+g)*128+d][t] bf16
// ---------------------------------------------------------------------------
__global__ __launch_bounds__(256) void vtrans_kernel(
    const unsigned short* __restrict__ v, unsigned short* __restrict__ vt)
{
    __shared__ unsigned short tile[64][68];
    int bg = blockIdx.z;           // b*4+g
    int b = bg >> 2, g = bg & 3;
    int t0 = blockIdx.x * 64;
    int d0 = blockIdx.y * 64;
    int tx = threadIdx.x & 15, ty = threadIdx.x >> 4;
#pragma unroll
    for (int i = 0; i < 4; ++i) {
        int r = ty + i * 16;
        ushort4 v4 = *(const ushort4*)&v[(size_t)(b * TT + t0 + r) * (HKK * HD) + g * HD + d0 + tx * 4];
        tile[r][tx * 4 + 0] = v4.x;
        tile[r][tx * 4 + 1] = v4.y;
        tile[r][tx * 4 + 2] = v4.z;
        tile[r][tx * 4 + 3] = v4.w;
    }
    __syncthreads();
#pragma unroll
    for (int i = 0; i < 4; ++i) {
        int r = ty + i * 16;   // d-local
        int c = tx * 4;        // t-local
        ushort4 o;
        o.x = tile[c + 0][r];
        o.y = tile[c + 1][r];
        o.z = tile[c + 2][r];
        o.w = tile[c + 3][r];
        *(ushort4*)&vt[(size_t)(bg * HD + d0 + r) * TT + t0 + c] = o;
    }
}

// ---------------------------------------------------------------------------
// MFMA flash attention. Block = 4 waves, BR=64 (16 q-rows/wave), BC=64.
// K LDS [tok][d] stride 136; Vt LDS [d][tok] stride 72; P LDS per-wave
// [16][72].  Q frags live in registers.  All MFMA 16x16x32 bf16.
// ---------------------------------------------------------------------------
__global__ __launch_bounds__(256) void flash_mfma(
    const unsigned short* __restrict__ q, const unsigned short* __restrict__ k,
    const unsigned short* __restrict__ vt, unsigned short* __restrict__ y)
{
    __shared__ __attribute__((aligned(16))) short Ks[64 * 136];
    __shared__ __attribute__((aligned(16))) short Vs[128 * 72];
    __shared__ __attribute__((aligned(16))) short Ps[4 * 16 * 72];

    const int tid = threadIdx.x;
    const int lane = tid & 63;
    const int w = tid >> 6;
    const int lm = lane & 15;
    const int q8 = lane >> 4;
    const int qi = blockIdx.x;            // q tile (64 rows)
    const int bh = blockIdx.y;            // 0..31
    const int b = bh >> 4, h = bh & 15, g = h >> 2;
    const int q0 = qi * 64;
    const int wrow = w * 16;
    const float scale = 0.08838834764831845f;   // 1/sqrt(128)

    // Q fragments: A-layout, 4 k-steps of 32
    bf16x8 qf[4];
#pragma unroll
    for (int ks = 0; ks < 4; ++ks)
        qf[ks] = *(const bf16x8*)&q[(size_t)(b * TT + q0 + wrow + lm) * CC + h * HD + ks * 32 + q8 * 8];

    f32x4 o_acc[8];
#pragma unroll
    for (int nt = 0; nt < 8; ++nt) o_acc[nt] = {0.f, 0.f, 0.f, 0.f};
    float m_i[4], l_i[4];
#pragma unroll
    for (int r = 0; r < 4; ++r) { m_i[r] = -1e30f; l_i[r] = 0.f; }

    short* Pw = Ps + w * 16 * 72;

    for (int j = 0; j <= qi; ++j) {
        __syncthreads();   // prior iter's K/V reads done
        // Stage K tile (64 tok x 128 d = 1024 x 16B) and Vt tile (128 d x 64 tok
        // = 1024 x 16B): 4 chunks each per thread.
#pragma unroll
        for (int i = 0; i < 4; ++i) {
            int f = tid + i * 256;              // 0..1023
            int tok = f >> 4, e8 = (f & 15) * 8;
            *(uint4*)&Ks[tok * 136 + e8] =
                *(const uint4*)&k[(size_t)(b * TT + j * 64 + tok) * (HKK * HD) + g * HD + e8];
            int d = f >> 3, t8 = (f & 7) * 8;
            *(uint4*)&Vs[d * 72 + t8] =
                *(const uint4*)&vt[(size_t)((b * 4 + g) * HD + d) * TT + j * 64 + t8];
        }
        __syncthreads();

        // S = Q K^T : 4 col-tiles of 16 tokens
        f32x4 sacc[4];
#pragma unroll
        for (int ct = 0; ct < 4; ++ct) {
            sacc[ct] = {0.f, 0.f, 0.f, 0.f};
#pragma unroll
            for (int ks = 0; ks < 4; ++ks) {
                bf16x8 kf = *(const bf16x8*)&Ks[(ct * 16 + lm) * 136 + ks * 32 + q8 * 8];
                sacc[ct] = __builtin_amdgcn_mfma_f32_16x16x32_bf16(qf[ks], kf, sacc[ct], 0, 0, 0);
            }
        }

        const bool diag = (j == qi);
#pragma unroll
        for (int ct = 0; ct < 4; ++ct) {
            int col = j * 64 + ct * 16 + lm;
#pragma unroll
            for (int r = 0; r < 4; ++r) {
                float s = sacc[ct][r] * scale;
                if (diag && col > (q0 + wrow + q8 * 4 + r)) s = -1e30f;
                sacc[ct][r] = s;
            }
        }

        float tmax[4];
#pragma unroll
        for (int r = 0; r < 4; ++r)
            tmax[r] = fmaxf(fmaxf(sacc[0][r], sacc[1][r]), fmaxf(sacc[2][r], sacc[3][r]));
        for (int o = 1; o < 16; o <<= 1)
#pragma unroll
            for (int r = 0; r < 4; ++r) tmax[r] = fmaxf(tmax[r], __shfl_xor(tmax[r], o));

        float alpha[4], psum[4];
#pragma unroll
        for (int r = 0; r < 4; ++r) {
            float m_new = fmaxf(m_i[r], tmax[r]);
            alpha[r] = __expf(m_i[r] - m_new);
            m_i[r] = m_new;
            psum[r] = 0.f;
        }
#pragma unroll
        for (int ct = 0; ct < 4; ++ct)
#pragma unroll
            for (int r = 0; r < 4; ++r) {
                float p = __expf(sacc[ct][r] - m_i[r]);
                psum[r] += p;
                Pw[(q8 * 4 + r) * 72 + ct * 16 + lm] = (short)f2bf(p);
            }
        for (int o = 1; o < 16; o <<= 1)
#pragma unroll
            for (int r = 0; r < 4; ++r) psum[r] += __shfl_xor(psum[r], o);
#pragma unroll
        for (int r = 0; r < 4; ++r) l_i[r] = l_i[r] * alpha[r] + psum[r];

#pragma unroll
        for (int nt = 0; nt < 8; ++nt)
#pragma unroll
            for (int r = 0; r < 4; ++r) o_acc[nt][r] *= alpha[r];

        __syncthreads();   // P writes visible before A-frag reads

        // O += P V : P is A-operand (2 k-steps of 32 tokens), Vs rows are B-frags
#pragma unroll
        for (int ks = 0; ks < 2; ++ks) {
            bf16x8 pf = *(const bf16x8*)&Pw[lm * 72 + ks * 32 + q8 * 8];
#pragma unroll
            for (int nt = 0; nt < 8; ++nt) {
                bf16x8 vf = *(const bf16x8*)&Vs[(nt * 16 + lm) * 72 + ks * 32 + q8 * 8];
                o_acc[nt] = __builtin_amdgcn_mfma_f32_16x16x32_bf16(pf, vf, o_acc[nt], 0, 0, 0);
            }
        }
    }

    float inv[4];
#pragma unroll
    for (int r = 0; r < 4; ++r) inv[r] = 1.f / l_i[r];
#pragma unroll
    for (int nt = 0; nt < 8; ++nt)
#pragma unroll
        for (int r = 0; r < 4; ++r) {
            int rowg = q0 + wrow + q8 * 4 + r;
            y[(size_t)(b * TT + rowg) * CC + h * HD + nt * 16 + lm] = f2bf(o_acc[nt][r] * inv[r]);
        }
}

// ---------------------------------------------------------------------------
extern "C" void kernel_launch(void* const* d_in, const int* in_sizes, int n_in,
                              void* d_out, int out_size, void* d_ws, size_t ws_size,
                              hipStream_t stream) {
    const float* x    = (const float*)d_in[0];
    const float* cosb = (const float*)d_in[1];
    const float* sinb = (const float*)d_in[2];
    const float* Wq   = (const float*)d_in[3];
    const float* bq   = (const float*)d_in[4];
    const float* Wk   = (const float*)d_in[5];
    const float* bk   = (const float*)d_in[6];
    const float* Wv   = (const float*)d_in[7];
    const float* bv   = (const float*)d_in[8];
    const float* Wo   = (const float*)d_in[9];
    float* out = (float*)d_out;

    // workspace (all bf16 as ushort):
    // xb[4096*2048] Wt[3072*2048] Wot[2048*2048] qb[4096*2048]
    // kb[4096*512] vb[4096*512] vtb[1024*2048] yb[4096*2048]  = 83.9 MB
    unsigned short* xb  = (unsigned short*)d_ws;
    unsigned short* Wt  = xb  + (size_t)MM * CC;
    unsigned short* Wot = Wt  + (size_t)3072 * 2048;
    unsigned short* qb  = Wot + (size_t)2048 * 2048;
    unsigned short* kb  = qb  + (size_t)MM * CC;
    unsigned short* vb  = kb  + (size_t)MM * (HKK * HD);
    unsigned short* vtb = vb  + (size_t)MM * (HKK * HD);
    unsigned short* ybf = vtb + (size_t)BB * HKK * HD * TT;

    cast_x_kernel<<<dim3((MM * CC) / 2048), 256, 0, stream>>>(x, xb);
    wtrans_kernel<<<dim3(32, 32, 4), 256, 0, stream>>>(Wq, Wk, Wv, Wo, Wt, Wot);
    qkv_gemm_mfma<<<dim3(3072 / 128, MM / 128), 256, 0, stream>>>(xb, Wt, bq, bk, bv, qb, kb, vb);
    rope_bf<<<dim3((MM * 20) / 4), 256, 0, stream>>>(qb, kb, cosb, sinb);
    vtrans_kernel<<<dim3(TT / 64, HD / 64, BB * HKK), 256, 0, stream>>>(vb, vtb);
    flash_mfma<<<dim3(TT / 64, BB * HH), 256, 0, stream>>>(qb, kb, vtb, ybf);
    out_gemm_mfma<<<dim3(CC / 128, MM / 128), 256, 0, stream>>>(ybf, Wot, out);
}

// Round 4
// 440.710 us; speedup vs baseline: 6.8025x; 1.2759x over previous
//
#include <hip/hip_runtime.h>
#include <math.h>

// Problem constants
#define BB 2
#define TT 2048
#define CC 2048
#define HH 16
#define HKK 4
#define HD 128
#define MM (BB*TT)          // 4096 rows

typedef short bf16x8 __attribute__((ext_vector_type(8)));
typedef float f32x4 __attribute__((ext_vector_type(4)));

__device__ __forceinline__ unsigned short f2bf(float f) {
    unsigned u = __float_as_uint(f);
    u += 0x7fff + ((u >> 16) & 1);          // round-to-nearest-even
    return (unsigned short)(u >> 16);
}
__device__ __forceinline__ float bf2f(unsigned short h) {
    return __uint_as_float(((unsigned)h) << 16);
}

// ---------------------------------------------------------------------------
// cast x (f32 -> bf16), 8 elements/thread
// ---------------------------------------------------------------------------
__global__ __launch_bounds__(256) void cast_x_kernel(
    const float* __restrict__ x, unsigned short* __restrict__ xb)
{
    size_t i = ((size_t)blockIdx.x * 256 + threadIdx.x) * 8;
    float4 a = *(const float4*)&x[i];
    float4 b = *(const float4*)&x[i + 4];
    uint4 r;
    r.x = f2bf(a.x) | ((unsigned)f2bf(a.y) << 16);
    r.y = f2bf(a.z) | ((unsigned)f2bf(a.w) << 16);
    r.z = f2bf(b.x) | ((unsigned)f2bf(b.y) << 16);
    r.w = f2bf(b.z) | ((unsigned)f2bf(b.w) << 16);
    *(uint4*)&xb[i] = r;
}

// ---------------------------------------------------------------------------
// Weight transpose+cast: W[K][N] f32 -> Wt[N][K] bf16.
// ---------------------------------------------------------------------------
__global__ __launch_bounds__(256) void wtrans_kernel(
    const float* __restrict__ Wq, const float* __restrict__ Wk,
    const float* __restrict__ Wv, const float* __restrict__ Wo,
    unsigned short* __restrict__ Wt, unsigned short* __restrict__ Wot)
{
    __shared__ float tile[64][65];
    int z = blockIdx.z;
    const float* src; unsigned short* dst; int ldW, nmax, noff;
    if (z == 0)      { src = Wq; dst = Wt;  ldW = 2048; nmax = 2048; noff = 0; }
    else if (z == 1) { src = Wk; dst = Wt;  ldW = 512;  nmax = 512;  noff = 2048; }
    else if (z == 2) { src = Wv; dst = Wt;  ldW = 512;  nmax = 512;  noff = 2560; }
    else             { src = Wo; dst = Wot; ldW = 2048; nmax = 2048; noff = 0; }
    int n0 = blockIdx.y * 64;
    if (n0 >= nmax) return;
    int k0 = blockIdx.x * 64;
    int tx = threadIdx.x & 15, ty = threadIdx.x >> 4;
#pragma unroll
    for (int i = 0; i < 4; ++i) {
        int r = ty + i * 16;
        float4 v4 = *(const float4*)&src[(size_t)(k0 + r) * ldW + n0 + tx * 4];
        tile[r][tx * 4 + 0] = v4.x;
        tile[r][tx * 4 + 1] = v4.y;
        tile[r][tx * 4 + 2] = v4.z;
        tile[r][tx * 4 + 3] = v4.w;
    }
    __syncthreads();
#pragma unroll
    for (int i = 0; i < 4; ++i) {
        int r = ty + i * 16;     // n-local
        int c = tx * 4;          // k-local
        ushort4 o;
        o.x = f2bf(tile[c + 0][r]);
        o.y = f2bf(tile[c + 1][r]);
        o.z = f2bf(tile[c + 2][r]);
        o.w = f2bf(tile[c + 3][r]);
        *(ushort4*)&dst[(size_t)(noff + n0 + r) * 2048 + k0 + c] = o;
    }
}

// ---------------------------------------------------------------------------
// MFMA GEMM 128x128x32 tile, 4 waves (2x2), 16x16x32 bf16, single-buffered.
// ---------------------------------------------------------------------------
__global__ __launch_bounds__(256) void qkv_gemm_mfma(
    const unsigned short* __restrict__ xb, const unsigned short* __restrict__ Wt,
    const float* __restrict__ bq, const float* __restrict__ bk, const float* __restrict__ bv,
    unsigned short* __restrict__ q, unsigned short* __restrict__ k, unsigned short* __restrict__ v)
{
    __shared__ __attribute__((aligned(16))) short As[128 * 32];
    __shared__ __attribute__((aligned(16))) short Bs[128 * 32];
    const int tid = threadIdx.x;
    const int lane = tid & 63;
    const int w = tid >> 6;
    const int wm = (w & 1) * 64;
    const int wn = (w >> 1) * 64;
    const int m0 = blockIdx.y * 128;
    const int n0 = blockIdx.x * 128;
    const int lm = lane & 15;
    const int q8 = lane >> 4;

    f32x4 acc[4][4];
#pragma unroll
    for (int im = 0; im < 4; ++im)
#pragma unroll
        for (int in = 0; in < 4; ++in) acc[im][in] = {0.f, 0.f, 0.f, 0.f};

    const int srow = tid >> 2;          // 0..63
    const int sk8 = (tid & 3) * 8;      // k chunk offset (bf16)

    for (int kt = 0; kt < CC; kt += 32) {
        uint4 a0 = *(const uint4*)&xb[(size_t)(m0 + srow) * CC + kt + sk8];
        uint4 a1 = *(const uint4*)&xb[(size_t)(m0 + 64 + srow) * CC + kt + sk8];
        uint4 b0 = *(const uint4*)&Wt[(size_t)(n0 + srow) * CC + kt + sk8];
        uint4 b1 = *(const uint4*)&Wt[(size_t)(n0 + 64 + srow) * CC + kt + sk8];
        __syncthreads();
        ((uint4*)As)[tid] = a0;
        ((uint4*)As)[tid + 256] = a1;
        ((uint4*)Bs)[tid] = b0;
        ((uint4*)Bs)[tid + 256] = b1;
        __syncthreads();
        bf16x8 af[4], bf[4];
#pragma unroll
        for (int i = 0; i < 4; ++i) {
            af[i] = *(const bf16x8*)&As[(wm + i * 16 + lm) * 32 + q8 * 8];
            bf[i] = *(const bf16x8*)&Bs[(wn + i * 16 + lm) * 32 + q8 * 8];
        }
#pragma unroll
        for (int im = 0; im < 4; ++im)
#pragma unroll
            for (int in = 0; in < 4; ++in)
                acc[im][in] = __builtin_amdgcn_mfma_f32_16x16x32_bf16(af[im], bf[in], acc[im][in], 0, 0, 0);
    }

    unsigned short* dst; const float* bias; int ldD, off;
    if (n0 < 2048)      { dst = q; bias = bq; ldD = 2048; off = n0; }
    else if (n0 < 2560) { dst = k; bias = bk; ldD = 512;  off = n0 - 2048; }
    else                { dst = v; bias = bv; ldD = 512;  off = n0 - 2560; }

#pragma unroll
    for (int in = 0; in < 4; ++in) {
        float bias_v = bias[off + wn + in * 16 + lm];
#pragma unroll
        for (int im = 0; im < 4; ++im) {
#pragma unroll
            for (int r = 0; r < 4; ++r) {
                int row = m0 + wm + im * 16 + q8 * 4 + r;   // C/D: row = quad*4+reg
                dst[(size_t)row * ldD + off + wn + in * 16 + lm] = f2bf(acc[im][in][r] + bias_v);
            }
        }
    }
}

__global__ __launch_bounds__(256) void out_gemm_mfma(
    const unsigned short* __restrict__ yb, const unsigned short* __restrict__ Wot,
    float* __restrict__ Cout)
{
    __shared__ __attribute__((aligned(16))) short As[128 * 32];
    __shared__ __attribute__((aligned(16))) short Bs[128 * 32];
    const int tid = threadIdx.x;
    const int lane = tid & 63;
    const int w = tid >> 6;
    const int wm = (w & 1) * 64;
    const int wn = (w >> 1) * 64;
    const int m0 = blockIdx.y * 128;
    const int n0 = blockIdx.x * 128;
    const int lm = lane & 15;
    const int q8 = lane >> 4;

    f32x4 acc[4][4];
#pragma unroll
    for (int im = 0; im < 4; ++im)
#pragma unroll
        for (int in = 0; in < 4; ++in) acc[im][in] = {0.f, 0.f, 0.f, 0.f};

    const int srow = tid >> 2;
    const int sk8 = (tid & 3) * 8;

    for (int kt = 0; kt < CC; kt += 32) {
        uint4 a0 = *(const uint4*)&yb[(size_t)(m0 + srow) * CC + kt + sk8];
        uint4 a1 = *(const uint4*)&yb[(size_t)(m0 + 64 + srow) * CC + kt + sk8];
        uint4 b0 = *(const uint4*)&Wot[(size_t)(n0 + srow) * CC + kt + sk8];
        uint4 b1 = *(const uint4*)&Wot[(size_t)(n0 + 64 + srow) * CC + kt + sk8];
        __syncthreads();
        ((uint4*)As)[tid] = a0;
        ((uint4*)As)[tid + 256] = a1;
        ((uint4*)Bs)[tid] = b0;
        ((uint4*)Bs)[tid + 256] = b1;
        __syncthreads();
        bf16x8 af[4], bf[4];
#pragma unroll
        for (int i = 0; i < 4; ++i) {
            af[i] = *(const bf16x8*)&As[(wm + i * 16 + lm) * 32 + q8 * 8];
            bf[i] = *(const bf16x8*)&Bs[(wn + i * 16 + lm) * 32 + q8 * 8];
        }
#pragma unroll
        for (int im = 0; im < 4; ++im)
#pragma unroll
            for (int in = 0; in < 4; ++in)
                acc[im][in] = __builtin_amdgcn_mfma_f32_16x16x32_bf16(af[im], bf[in], acc[im][in], 0, 0, 0);
    }

#pragma unroll
    for (int im = 0; im < 4; ++im)
#pragma unroll
        for (int in = 0; in < 4; ++in)
#pragma unroll
            for (int r = 0; r < 4; ++r) {
                int row = m0 + wm + im * 16 + q8 * 4 + r;
                Cout[(size_t)row * CC + n0 + wn + in * 16 + lm] = acc[im][in][r];
            }
}

// ---------------------------------------------------------------------------
// RoPE in place on bf16 q (16 heads) and k (4 heads).
// ---------------------------------------------------------------------------
__global__ __launch_bounds__(256) void rope_bf(
    unsigned short* __restrict__ q, unsigned short* __restrict__ k,
    const float* __restrict__ cosb, const float* __restrict__ sinb)
{
    int slot = blockIdx.x * 4 + (threadIdx.x >> 6);  // 0 .. MM*20-1
    int d = threadIdx.x & 63;
    int row = slot / 20;
    int s = slot - row * 20;
    unsigned short* p = (s < 16) ? (q + (size_t)row * CC + s * HD)
                                 : (k + (size_t)row * (HKK * HD) + (s - 16) * HD);
    float c1 = cosb[row * HD + d],      s1 = sinb[row * HD + d];
    float c2 = cosb[row * HD + 64 + d], s2 = sinb[row * HD + 64 + d];
    float x1 = bf2f(p[d]);
    float x2 = bf2f(p[d + 64]);
    p[d]      = f2bf(x1 * c1 - x2 * s1);
    p[d + 64] = f2bf(x2 * c2 + x1 * s2);
}

// ---------------------------------------------------------------------------
// V transpose: v[b][t][g*128+d] bf16 -> vt[(b*4+g)*128+d][t] bf16
// ---------------------------------------------------------------------------
__global__ __launch_bounds__(256) void vtrans_kernel(
    const unsigned short* __restrict__ v, unsigned short* __restrict__ vt)
{
    __shared__ unsigned short tile[64][68];
    int bg = blockIdx.z;           // b*4+g
    int b = bg >> 2, g = bg & 3;
    int t0 = blockIdx.x * 64;
    int d0 = blockIdx.y * 64;
    int tx = threadIdx.x & 15, ty = threadIdx.x >> 4;
#pragma unroll
    for (int i = 0; i < 4; ++i) {
        int r = ty + i * 16;
        ushort4 v4 = *(const ushort4*)&v[(size_t)(b * TT + t0 + r) * (HKK * HD) + g * HD + d0 + tx * 4];
        tile[r][tx * 4 + 0] = v4.x;
        tile[r][tx * 4 + 1] = v4.y;
        tile[r][tx * 4 + 2] = v4.z;
        tile[r][tx * 4 + 3] = v4.w;
    }
    __syncthreads();
#pragma unroll
    for (int i = 0; i < 4; ++i) {
        int r = ty + i * 16;   // d-local
        int c = tx * 4;        // t-local
        ushort4 o;
        o.x = tile[c + 0][r];
        o.y = tile[c + 1][r];
        o.z = tile[c + 2][r];
        o.w = tile[c + 3][r];
        *(ushort4*)&vt[(size_t)(bg * HD + d0 + r) * TT + t0 + c] = o;
    }
}

// ---------------------------------------------------------------------------
// MFMA flash attention, BR=128.  Block = 4 waves; each wave owns two 16-row
// tiles (rt=0/1 at rows rt*64 + w*16) of ONE head.  BC=64.  K LDS [tok][d]
// stride 136; Vt LDS [d][tok] stride 72; P per (wave,rt) [16][72].
// Register prefetch of next K/V tile hides global latency across the
// loop-top barrier; only 2 barriers per j-iter (P is wave-private).
// Grid: x=bh (32), y paired long+short q-strips for balance (512 blocks
// = exactly 2/CU, all resident; LDS 54272 B).
// ---------------------------------------------------------------------------
__global__ __launch_bounds__(256, 2) void flash_mfma(
    const unsigned short* __restrict__ q, const unsigned short* __restrict__ k,
    const unsigned short* __restrict__ vt, unsigned short* __restrict__ y)
{
    __shared__ __attribute__((aligned(16))) short Ks[64 * 136];    // 17408 B
    __shared__ __attribute__((aligned(16))) short Vs[128 * 72];    // 18432 B
    __shared__ __attribute__((aligned(16))) short Ps[8 * 16 * 72]; // 18432 B

    const int tid = threadIdx.x;
    const int lane = tid & 63;
    const int w = tid >> 6;
    const int lm = lane & 15;
    const int q8 = lane >> 4;
    const int bh = blockIdx.x;            // 0..31
    const int b = bh >> 4, h = bh & 15, g = h >> 2;
    const int yb_ = blockIdx.y;           // 0..15
    const int qi = (yb_ < 8) ? (15 - yb_) : (yb_ - 8);   // pair long+short
    const int q0 = qi * 128;
    const int wrow = w * 16;
    const int jmax = 2 * qi + 1;
    const float scale = 0.08838834764831845f;   // 1/sqrt(128)

    // Q fragments (A-layout), pre-scaled by 1/sqrt(HD): [rt][ks]
    bf16x8 qf[2][4];
#pragma unroll
    for (int rt = 0; rt < 2; ++rt)
#pragma unroll
        for (int ks = 0; ks < 4; ++ks) {
            bf16x8 t = *(const bf16x8*)&q[(size_t)(b * TT + q0 + rt * 64 + wrow + lm) * CC
                                          + h * HD + ks * 32 + q8 * 8];
#pragma unroll
            for (int e = 0; e < 8; ++e)
                t[e] = (short)f2bf(bf2f((unsigned short)t[e]) * scale);
            qf[rt][ks] = t;
        }

    f32x4 o_acc[2][8];
#pragma unroll
    for (int rt = 0; rt < 2; ++rt)
#pragma unroll
        for (int nt = 0; nt < 8; ++nt) o_acc[rt][nt] = {0.f, 0.f, 0.f, 0.f};
    float m_i[2][4], l_i[2][4];
#pragma unroll
    for (int rt = 0; rt < 2; ++rt)
#pragma unroll
        for (int r = 0; r < 4; ++r) { m_i[rt][r] = -1e30f; l_i[rt][r] = 0.f; }

    // staging geometry (loop-invariant): 1024 16B-chunks each for K and V
    int ktok[4], ke8[4], vd[4], vt8[4];
#pragma unroll
    for (int i = 0; i < 4; ++i) {
        int f = tid + i * 256;
        ktok[i] = f >> 4; ke8[i] = (f & 15) * 8;
        vd[i]   = f >> 3; vt8[i] = (f & 7) * 8;
    }
    const unsigned short* kbase = k + (size_t)(b * TT) * (HKK * HD) + g * HD;
    const unsigned short* vbase = vt + (size_t)((b * 4 + g) * HD) * TT;

    uint4 kreg[4], vreg[4];
#pragma unroll
    for (int i = 0; i < 4; ++i) {
        kreg[i] = *(const uint4*)&kbase[(size_t)(0 * 64 + ktok[i]) * (HKK * HD) + ke8[i]];
        vreg[i] = *(const uint4*)&vbase[(size_t)vd[i] * TT + 0 * 64 + vt8[i]];
    }

    for (int j = 0; j <= jmax; ++j) {
        __syncthreads();                 // prev iter's K/V LDS reads complete
#pragma unroll
        for (int i = 0; i < 4; ++i) {
            *(uint4*)&Ks[ktok[i] * 136 + ke8[i]] = kreg[i];
            *(uint4*)&Vs[vd[i] * 72 + vt8[i]]    = vreg[i];
        }
        __syncthreads();                 // tiles visible
        if (j < jmax) {                  // prefetch next tile (uniform branch)
#pragma unroll
            for (int i = 0; i < 4; ++i) {
                kreg[i] = *(const uint4*)&kbase[(size_t)((j + 1) * 64 + ktok[i]) * (HKK * HD) + ke8[i]];
                vreg[i] = *(const uint4*)&vbase[(size_t)vd[i] * TT + (j + 1) * 64 + vt8[i]];
            }
        }

#pragma unroll
        for (int rt = 0; rt < 2; ++rt) {
            if (j > 2 * qi + rt) continue;          // fully-masked row-tile
            // S = Q K^T
            f32x4 sacc[4];
#pragma unroll
            for (int ct = 0; ct < 4; ++ct) {
                sacc[ct] = {0.f, 0.f, 0.f, 0.f};
#pragma unroll
                for (int ks = 0; ks < 4; ++ks) {
                    bf16x8 kf = *(const bf16x8*)&Ks[(ct * 16 + lm) * 136 + ks * 32 + q8 * 8];
                    sacc[ct] = __builtin_amdgcn_mfma_f32_16x16x32_bf16(qf[rt][ks], kf, sacc[ct], 0, 0, 0);
                }
            }
            if (j == 2 * qi + rt) {                 // diagonal tile: causal mask
#pragma unroll
                for (int ct = 0; ct < 4; ++ct)
#pragma unroll
                    for (int r = 0; r < 4; ++r)
                        if (ct * 16 + lm > wrow + q8 * 4 + r) sacc[ct][r] = -1e30f;
            }
            // online softmax (rows live in 16-lane groups, same q8)
            float tmax[4];
#pragma unroll
            for (int r = 0; r < 4; ++r)
                tmax[r] = fmaxf(fmaxf(sacc[0][r], sacc[1][r]), fmaxf(sacc[2][r], sacc[3][r]));
            for (int o = 1; o < 16; o <<= 1)
#pragma unroll
                for (int r = 0; r < 4; ++r) tmax[r] = fmaxf(tmax[r], __shfl_xor(tmax[r], o));
            float alpha[4], psum[4];
#pragma unroll
            for (int r = 0; r < 4; ++r) {
                float m_new = fmaxf(m_i[rt][r], tmax[r]);
                alpha[r] = __expf(m_i[rt][r] - m_new);
                m_i[rt][r] = m_new;
                psum[r] = 0.f;
            }
#pragma unroll
            for (int ct = 0; ct < 4; ++ct)
#pragma unroll
                for (int r = 0; r < 4; ++r) {
                    float p = __expf(sacc[ct][r] - m_i[rt][r]);
                    psum[r] += p;
                    Ps[((w * 2 + rt) * 16 + q8 * 4 + r) * 72 + ct * 16 + lm] = (short)f2bf(p);
                }
            for (int o = 1; o < 16; o <<= 1)
#pragma unroll
                for (int r = 0; r < 4; ++r) psum[r] += __shfl_xor(psum[r], o);
#pragma unroll
            for (int r = 0; r < 4; ++r) l_i[rt][r] = l_i[rt][r] * alpha[r] + psum[r];
#pragma unroll
            for (int nt = 0; nt < 8; ++nt)
#pragma unroll
                for (int r = 0; r < 4; ++r) o_acc[rt][nt][r] *= alpha[r];

            // O += P V  (P wave-private: no barrier, lgkmcnt ordering suffices)
#pragma unroll
            for (int ks2 = 0; ks2 < 2; ++ks2) {
                bf16x8 pf = *(const bf16x8*)&Ps[((w * 2 + rt) * 16 + lm) * 72 + ks2 * 32 + q8 * 8];
#pragma unroll
                for (int nt = 0; nt < 8; ++nt) {
                    bf16x8 vf = *(const bf16x8*)&Vs[(nt * 16 + lm) * 72 + ks2 * 32 + q8 * 8];
                    o_acc[rt][nt] = __builtin_amdgcn_mfma_f32_16x16x32_bf16(pf, vf, o_acc[rt][nt], 0, 0, 0);
                }
            }
        }
    }

#pragma unroll
    for (int rt = 0; rt < 2; ++rt) {
        float inv[4];
#pragma unroll
        for (int r = 0; r < 4; ++r) inv[r] = 1.f / l_i[rt][r];
#pragma unroll
        for (int nt = 0; nt < 8; ++nt)
#pragma unroll
            for (int r = 0; r < 4; ++r) {
                int rowg = q0 + rt * 64 + wrow + q8 * 4 + r;
                y[(size_t)(b * TT + rowg) * CC + h * HD + nt * 16 + lm] = f2bf(o_acc[rt][nt][r] * inv[r]);
            }
    }
}

// ---------------------------------------------------------------------------
extern "C" void kernel_launch(void* const* d_in, const int* in_sizes, int n_in,
                              void* d_out, int out_size, void* d_ws, size_t ws_size,
                              hipStream_t stream) {
    const float* x    = (const float*)d_in[0];
    const float* cosb = (const float*)d_in[1];
    const float* sinb = (const float*)d_in[2];
    const float* Wq   = (const float*)d_in[3];
    const float* bq   = (const float*)d_in[4];
    const float* Wk   = (const float*)d_in[5];
    const float* bk   = (const float*)d_in[6];
    const float* Wv   = (const float*)d_in[7];
    const float* bv   = (const float*)d_in[8];
    const float* Wo   = (const float*)d_in[9];
    float* out = (float*)d_out;

    // workspace (all bf16 as ushort):
    // xb[4096*2048] Wt[3072*2048] Wot[2048*2048] qb[4096*2048]
    // kb[4096*512] vb[4096*512] vtb[1024*2048] yb[4096*2048]  = 83.9 MB
    unsigned short* xb  = (unsigned short*)d_ws;
    unsigned short* Wt  = xb  + (size_t)MM * CC;
    unsigned short* Wot = Wt  + (size_t)3072 * 2048;
    unsigned short* qb  = Wot + (size_t)2048 * 2048;
    unsigned short* kb  = qb  + (size_t)MM * CC;
    unsigned short* vb  = kb  + (size_t)MM * (HKK * HD);
    unsigned short* vtb = vb  + (size_t)MM * (HKK * HD);
    unsigned short* ybf = vtb + (size_t)BB * HKK * HD * TT;

    cast_x_kernel<<<dim3((MM * CC) / 2048), 256, 0, stream>>>(x, xb);
    wtrans_kernel<<<dim3(32, 32, 4), 256, 0, stream>>>(Wq, Wk, Wv, Wo, Wt, Wot);
    qkv_gemm_mfma<<<dim3(3072 / 128, MM / 128), 256, 0, stream>>>(xb, Wt, bq, bk, bv, qb, kb, vb);
    rope_bf<<<dim3((MM * 20) / 4), 256, 0, stream>>>(qb, kb, cosb, sinb);
    vtrans_kernel<<<dim3(TT / 64, HD / 64, BB * HKK), 256, 0, stream>>>(vb, vtb);
    flash_mfma<<<dim3(BB * HH, TT / 128), 256, 0, stream>>>(qb, kb, vtb, ybf);
    out_gemm_mfma<<<dim3(CC / 128, MM / 128), 256, 0, stream>>>(ybf, Wot, out);
}

// Round 5
// 418.253 us; speedup vs baseline: 7.1677x; 1.0537x over previous
//
#include <hip/hip_runtime.h>
#include <math.h>

// Problem constants
#define BB 2
#define TT 2048
#define CC 2048
#define HH 16
#define HKK 4
#define HD 128
#define MM (BB*TT)          // 4096 rows

typedef short bf16x8 __attribute__((ext_vector_type(8)));
typedef float f32x4 __attribute__((ext_vector_type(4)));

#define GLOBAL_AS(p) ((const __attribute__((address_space(1))) void*)(p))
#define LDS_AS(p)    ((__attribute__((address_space(3))) void*)(p))

__device__ __forceinline__ unsigned short f2bf(float f) {
    unsigned u = __float_as_uint(f);
    u += 0x7fff + ((u >> 16) & 1);          // round-to-nearest-even
    return (unsigned short)(u >> 16);
}
__device__ __forceinline__ float bf2f(unsigned short h) {
    return __uint_as_float(((unsigned)h) << 16);
}

// ---------------------------------------------------------------------------
// cast x (f32 -> bf16), 8 elements/thread
// ---------------------------------------------------------------------------
__global__ __launch_bounds__(256) void cast_x_kernel(
    const float* __restrict__ x, unsigned short* __restrict__ xb)
{
    size_t i = ((size_t)blockIdx.x * 256 + threadIdx.x) * 8;
    float4 a = *(const float4*)&x[i];
    float4 b = *(const float4*)&x[i + 4];
    uint4 r;
    r.x = f2bf(a.x) | ((unsigned)f2bf(a.y) << 16);
    r.y = f2bf(a.z) | ((unsigned)f2bf(a.w) << 16);
    r.z = f2bf(b.x) | ((unsigned)f2bf(b.y) << 16);
    r.w = f2bf(b.z) | ((unsigned)f2bf(b.w) << 16);
    *(uint4*)&xb[i] = r;
}

// ---------------------------------------------------------------------------
// Weight transpose+cast: W[K][N] f32 -> Wt[N][K] bf16.
// ---------------------------------------------------------------------------
__global__ __launch_bounds__(256) void wtrans_kernel(
    const float* __restrict__ Wq, const float* __restrict__ Wk,
    const float* __restrict__ Wv, const float* __restrict__ Wo,
    unsigned short* __restrict__ Wt, unsigned short* __restrict__ Wot)
{
    __shared__ float tile[64][65];
    int z = blockIdx.z;
    const float* src; unsigned short* dst; int ldW, nmax, noff;
    if (z == 0)      { src = Wq; dst = Wt;  ldW = 2048; nmax = 2048; noff = 0; }
    else if (z == 1) { src = Wk; dst = Wt;  ldW = 512;  nmax = 512;  noff = 2048; }
    else if (z == 2) { src = Wv; dst = Wt;  ldW = 512;  nmax = 512;  noff = 2560; }
    else             { src = Wo; dst = Wot; ldW = 2048; nmax = 2048; noff = 0; }
    int n0 = blockIdx.y * 64;
    if (n0 >= nmax) return;
    int k0 = blockIdx.x * 64;
    int tx = threadIdx.x & 15, ty = threadIdx.x >> 4;
#pragma unroll
    for (int i = 0; i < 4; ++i) {
        int r = ty + i * 16;
        float4 v4 = *(const float4*)&src[(size_t)(k0 + r) * ldW + n0 + tx * 4];
        tile[r][tx * 4 + 0] = v4.x;
        tile[r][tx * 4 + 1] = v4.y;
        tile[r][tx * 4 + 2] = v4.z;
        tile[r][tx * 4 + 3] = v4.w;
    }
    __syncthreads();
#pragma unroll
    for (int i = 0; i < 4; ++i) {
        int r = ty + i * 16;     // n-local
        int c = tx * 4;          // k-local
        ushort4 o;
        o.x = f2bf(tile[c + 0][r]);
        o.y = f2bf(tile[c + 1][r]);
        o.z = f2bf(tile[c + 2][r]);
        o.w = f2bf(tile[c + 3][r]);
        *(ushort4*)&dst[(size_t)(noff + n0 + r) * 2048 + k0 + c] = o;
    }
}

// ---------------------------------------------------------------------------
// MFMA GEMM 128x128x64 tile, 4 waves (2x2), 16x16x32 bf16.
// Staging via global_load_lds (16B/lane, 1KB/instr, 8 instr/wave/iter).
// LDS rows are [row][64k] dense (required by direct-to-LDS); the k-chunk
// (8 bf16) is XOR-swizzled by row&7 so b128 frag reads hit 8 distinct
// 4-bank groups (conflict-free 8-phase minimum).
// ---------------------------------------------------------------------------
__device__ __forceinline__ void gemm_core_128x128x64(
    const unsigned short* __restrict__ A, const unsigned short* __restrict__ B,
    short* As, short* Bs, int m0, int n0, f32x4 (&acc)[4][4])
{
    const int tid = threadIdx.x;
    const int lane = tid & 63;
    const int w = tid >> 6;
    const int wm = (w & 1) * 64;
    const int wn = (w >> 1) * 64;
    const int lm = lane & 15;
    const int q8 = lane >> 4;

    const int lrow = lane >> 3;            // 0..7 within an instr's 8 rows
    const int lchunk = lane & 7;           // lane's LDS chunk slot

    for (int kt = 0; kt < CC; kt += 64) {
        __syncthreads();                   // prev iter frag reads complete
#pragma unroll
        for (int jj = 0; jj < 4; ++jj) {
            int rA = w * 32 + jj * 8 + lrow;
            int cA = ((lchunk ^ (rA & 7)) << 3);
            __builtin_amdgcn_global_load_lds(
                GLOBAL_AS(&A[(size_t)(m0 + rA) * CC + kt + cA]),
                LDS_AS(&As[(w * 32 + jj * 8) * 64]), 16, 0, 0);
            __builtin_amdgcn_global_load_lds(
                GLOBAL_AS(&B[(size_t)(n0 + rA) * CC + kt + cA]),
                LDS_AS(&Bs[(w * 32 + jj * 8) * 64]), 16, 0, 0);
        }
        __syncthreads();                   // vmcnt drained -> tiles visible
#pragma unroll
        for (int ksi = 0; ksi < 2; ++ksi) {
            bf16x8 af[4], bf[4];
#pragma unroll
            for (int i = 0; i < 4; ++i) {
                int xo = (((ksi * 4 + q8) ^ (lm & 7)) << 3);
                af[i] = *(const bf16x8*)&As[(wm + i * 16 + lm) * 64 + xo];
                bf[i] = *(const bf16x8*)&Bs[(wn + i * 16 + lm) * 64 + xo];
            }
#pragma unroll
            for (int im = 0; im < 4; ++im)
#pragma unroll
                for (int in = 0; in < 4; ++in)
                    acc[im][in] = __builtin_amdgcn_mfma_f32_16x16x32_bf16(af[im], bf[in], acc[im][in], 0, 0, 0);
        }
    }
}

__global__ __launch_bounds__(256, 3) void qkv_gemm_mfma(
    const unsigned short* __restrict__ xb, const unsigned short* __restrict__ Wt,
    const float* __restrict__ bq, const float* __restrict__ bk, const float* __restrict__ bv,
    unsigned short* __restrict__ q, unsigned short* __restrict__ k, unsigned short* __restrict__ v)
{
    __shared__ __attribute__((aligned(16))) short As[128 * 64];
    __shared__ __attribute__((aligned(16))) short Bs[128 * 64];
    const int lane = threadIdx.x & 63;
    const int w = threadIdx.x >> 6;
    const int wm = (w & 1) * 64;
    const int wn = (w >> 1) * 64;
    const int m0 = blockIdx.y * 128;
    const int n0 = blockIdx.x * 128;
    const int lm = lane & 15;
    const int q8 = lane >> 4;

    f32x4 acc[4][4];
#pragma unroll
    for (int im = 0; im < 4; ++im)
#pragma unroll
        for (int in = 0; in < 4; ++in) acc[im][in] = {0.f, 0.f, 0.f, 0.f};

    gemm_core_128x128x64(xb, Wt, As, Bs, m0, n0, acc);

    unsigned short* dst; const float* bias; int ldD, off;
    if (n0 < 2048)      { dst = q; bias = bq; ldD = 2048; off = n0; }
    else if (n0 < 2560) { dst = k; bias = bk; ldD = 512;  off = n0 - 2048; }
    else                { dst = v; bias = bv; ldD = 512;  off = n0 - 2560; }

#pragma unroll
    for (int in = 0; in < 4; ++in) {
        float bias_v = bias[off + wn + in * 16 + lm];
#pragma unroll
        for (int im = 0; im < 4; ++im) {
#pragma unroll
            for (int r = 0; r < 4; ++r) {
                int row = m0 + wm + im * 16 + q8 * 4 + r;   // C/D: row = quad*4+reg
                dst[(size_t)row * ldD + off + wn + in * 16 + lm] = f2bf(acc[im][in][r] + bias_v);
            }
        }
    }
}

__global__ __launch_bounds__(256, 3) void out_gemm_mfma(
    const unsigned short* __restrict__ yb, const unsigned short* __restrict__ Wot,
    float* __restrict__ Cout)
{
    __shared__ __attribute__((aligned(16))) short As[128 * 64];
    __shared__ __attribute__((aligned(16))) short Bs[128 * 64];
    const int lane = threadIdx.x & 63;
    const int w = threadIdx.x >> 6;
    const int wm = (w & 1) * 64;
    const int wn = (w >> 1) * 64;
    const int m0 = blockIdx.y * 128;
    const int n0 = blockIdx.x * 128;
    const int lm = lane & 15;
    const int q8 = lane >> 4;

    f32x4 acc[4][4];
#pragma unroll
    for (int im = 0; im < 4; ++im)
#pragma unroll
        for (int in = 0; in < 4; ++in) acc[im][in] = {0.f, 0.f, 0.f, 0.f};

    gemm_core_128x128x64(yb, Wot, As, Bs, m0, n0, acc);

#pragma unroll
    for (int im = 0; im < 4; ++im)
#pragma unroll
        for (int in = 0; in < 4; ++in)
#pragma unroll
            for (int r = 0; r < 4; ++r) {
                int row = m0 + wm + im * 16 + q8 * 4 + r;
                Cout[(size_t)row * CC + n0 + wn + in * 16 + lm] = acc[im][in][r];
            }
}

// ---------------------------------------------------------------------------
// RoPE in place on bf16 q (16 heads) and k (4 heads).
// ---------------------------------------------------------------------------
__global__ __launch_bounds__(256) void rope_bf(
    unsigned short* __restrict__ q, unsigned short* __restrict__ k,
    const float* __restrict__ cosb, const float* __restrict__ sinb)
{
    int slot = blockIdx.x * 4 + (threadIdx.x >> 6);  // 0 .. MM*20-1
    int d = threadIdx.x & 63;
    int row = slot / 20;
    int s = slot - row * 20;
    unsigned short* p = (s < 16) ? (q + (size_t)row * CC + s * HD)
                                 : (k + (size_t)row * (HKK * HD) + (s - 16) * HD);
    float c1 = cosb[row * HD + d],      s1 = sinb[row * HD + d];
    float c2 = cosb[row * HD + 64 + d], s2 = sinb[row * HD + 64 + d];
    float x1 = bf2f(p[d]);
    float x2 = bf2f(p[d + 64]);
    p[d]      = f2bf(x1 * c1 - x2 * s1);
    p[d + 64] = f2bf(x2 * c2 + x1 * s2);
}

// ---------------------------------------------------------------------------
// V transpose: v[b][t][g*128+d] bf16 -> vt[(b*4+g)*128+d][t] bf16
// ---------------------------------------------------------------------------
__global__ __launch_bounds__(256) void vtrans_kernel(
    const unsigned short* __restrict__ v, unsigned short* __restrict__ vt)
{
    __shared__ unsigned short tile[64][68];
    int bg = blockIdx.z;           // b*4+g
    int b = bg >> 2, g = bg & 3;
    int t0 = blockIdx.x * 64;
    int d0 = blockIdx.y * 64;
    int tx = threadIdx.x & 15, ty = threadIdx.x >> 4;
#pragma unroll
    for (int i = 0; i < 4; ++i) {
        int r = ty + i * 16;
        ushort4 v4 = *(const ushort4*)&v[(size_t)(b * TT + t0 + r) * (HKK * HD) + g * HD + d0 + tx * 4];
        tile[r][tx * 4 + 0] = v4.x;
        tile[r][tx * 4 + 1] = v4.y;
        tile[r][tx * 4 + 2] = v4.z;
        tile[r][tx * 4 + 3] = v4.w;
    }
    __syncthreads();
#pragma unroll
    for (int i = 0; i < 4; ++i) {
        int r = ty + i * 16;   // d-local
        int c = tx * 4;        // t-local
        ushort4 o;
        o.x = tile[c + 0][r];
        o.y = tile[c + 1][r];
        o.z = tile[c + 2][r];
        o.w = tile[c + 3][r];
        *(ushort4*)&vt[(size_t)(bg * HD + d0 + r) * TT + t0 + c] = o;
    }
}

// ---------------------------------------------------------------------------
// MFMA flash attention, BR=128, 512 threads (8 waves); wave w owns the
// 16-row strip q0 + w*16.  BC=64.  K LDS [tok][d] stride 136; Vt LDS
// [d][tok] stride 72; P per-wave [16][72].  Register prefetch of next
// K/V tile; 2 barriers per j-iter.  Grid 32 x 16 paired strips:
// 512 blocks = 2/CU -> 16 waves/CU (4/SIMD) for latency hiding.
// ---------------------------------------------------------------------------
__global__ __launch_bounds__(512, 4) void flash_mfma(
    const unsigned short* __restrict__ q, const unsigned short* __restrict__ k,
    const unsigned short* __restrict__ vt, unsigned short* __restrict__ y)
{
    __shared__ __attribute__((aligned(16))) short Ks[64 * 136];    // 17408 B
    __shared__ __attribute__((aligned(16))) short Vs[128 * 72];    // 18432 B
    __shared__ __attribute__((aligned(16))) short Ps[8 * 16 * 72]; // 18432 B

    const int tid = threadIdx.x;
    const int lane = tid & 63;
    const int w = tid >> 6;               // 0..7
    const int lm = lane & 15;
    const int q8 = lane >> 4;
    const int bh = blockIdx.x;            // 0..31
    const int b = bh >> 4, h = bh & 15, g = h >> 2;
    const int yb_ = blockIdx.y;           // 0..15
    const int qi = (yb_ < 8) ? (15 - yb_) : (yb_ - 8);   // pair long+short
    const int q0 = qi * 128;
    const int wrow = w * 16;
    const int jdiag = 2 * qi + (w >> 2);  // this wave's diagonal tile
    const int jmax = 2 * qi + 1;
    const float scale = 0.08838834764831845f;   // 1/sqrt(128)

    // Q fragments (A-layout), pre-scaled by 1/sqrt(HD)
    bf16x8 qf[4];
#pragma unroll
    for (int ks = 0; ks < 4; ++ks) {
        bf16x8 t = *(const bf16x8*)&q[(size_t)(b * TT + q0 + wrow + lm) * CC
                                      + h * HD + ks * 32 + q8 * 8];
#pragma unroll
        for (int e = 0; e < 8; ++e)
            t[e] = (short)f2bf(bf2f((unsigned short)t[e]) * scale);
        qf[ks] = t;
    }

    f32x4 o_acc[8];
#pragma unroll
    for (int nt = 0; nt < 8; ++nt) o_acc[nt] = {0.f, 0.f, 0.f, 0.f};
    float m_i[4], l_i[4];
#pragma unroll
    for (int r = 0; r < 4; ++r) { m_i[r] = -1e30f; l_i[r] = 0.f; }

    // staging geometry: 1024 16B-chunks each for K and V over 512 threads
    int ktok[2], ke8[2], vd[2], vt8[2];
#pragma unroll
    for (int i = 0; i < 2; ++i) {
        int f = tid + i * 512;
        ktok[i] = f >> 4; ke8[i] = (f & 15) * 8;
        vd[i]   = f >> 3; vt8[i] = (f & 7) * 8;
    }
    const unsigned short* kbase = k + (size_t)(b * TT) * (HKK * HD) + g * HD;
    const unsigned short* vbase = vt + (size_t)((b * 4 + g) * HD) * TT;

    uint4 kreg[2], vreg[2];
#pragma unroll
    for (int i = 0; i < 2; ++i) {
        kreg[i] = *(const uint4*)&kbase[(size_t)ktok[i] * (HKK * HD) + ke8[i]];
        vreg[i] = *(const uint4*)&vbase[(size_t)vd[i] * TT + vt8[i]];
    }

    short* Pw = Ps + w * 16 * 72;

    for (int j = 0; j <= jmax; ++j) {
        __syncthreads();                 // prev iter's K/V LDS reads complete
#pragma unroll
        for (int i = 0; i < 2; ++i) {
            *(uint4*)&Ks[ktok[i] * 136 + ke8[i]] = kreg[i];
            *(uint4*)&Vs[vd[i] * 72 + vt8[i]]    = vreg[i];
        }
        __syncthreads();                 // tiles visible
        if (j < jmax) {                  // prefetch next tile (uniform branch)
#pragma unroll
            for (int i = 0; i < 2; ++i) {
                kreg[i] = *(const uint4*)&kbase[(size_t)((j + 1) * 64 + ktok[i]) * (HKK * HD) + ke8[i]];
                vreg[i] = *(const uint4*)&vbase[(size_t)vd[i] * TT + (j + 1) * 64 + vt8[i]];
            }
        }

        if (j <= jdiag) {
            // S = Q K^T
            f32x4 sacc[4];
#pragma unroll
            for (int ct = 0; ct < 4; ++ct) {
                sacc[ct] = {0.f, 0.f, 0.f, 0.f};
#pragma unroll
                for (int ks = 0; ks < 4; ++ks) {
                    bf16x8 kf = *(const bf16x8*)&Ks[(ct * 16 + lm) * 136 + ks * 32 + q8 * 8];
                    sacc[ct] = __builtin_amdgcn_mfma_f32_16x16x32_bf16(qf[ks], kf, sacc[ct], 0, 0, 0);
                }
            }
            if (j == jdiag) {            // causal mask on diagonal tile
                int rbase = (w & 3) * 16 + q8 * 4;
#pragma unroll
                for (int ct = 0; ct < 4; ++ct)
#pragma unroll
                    for (int r = 0; r < 4; ++r)
                        if (ct * 16 + lm > rbase + r) sacc[ct][r] = -1e30f;
            }
            // online softmax (rows live in 16-lane groups, same q8)
            float tmax[4];
#pragma unroll
            for (int r = 0; r < 4; ++r)
                tmax[r] = fmaxf(fmaxf(sacc[0][r], sacc[1][r]), fmaxf(sacc[2][r], sacc[3][r]));
            for (int o = 1; o < 16; o <<= 1)
#pragma unroll
                for (int r = 0; r < 4; ++r) tmax[r] = fmaxf(tmax[r], __shfl_xor(tmax[r], o));
            float alpha[4], psum[4];
#pragma unroll
            for (int r = 0; r < 4; ++r) {
                float m_new = fmaxf(m_i[r], tmax[r]);
                alpha[r] = __expf(m_i[r] - m_new);
                m_i[r] = m_new;
                psum[r] = 0.f;
            }
#pragma unroll
            for (int ct = 0; ct < 4; ++ct)
#pragma unroll
                for (int r = 0; r < 4; ++r) {
                    float p = __expf(sacc[ct][r] - m_i[r]);
                    psum[r] += p;
                    Pw[(q8 * 4 + r) * 72 + ct * 16 + lm] = (short)f2bf(p);
                }
            for (int o = 1; o < 16; o <<= 1)
#pragma unroll
                for (int r = 0; r < 4; ++r) psum[r] += __shfl_xor(psum[r], o);
#pragma unroll
            for (int r = 0; r < 4; ++r) l_i[r] = l_i[r] * alpha[r] + psum[r];
#pragma unroll
            for (int nt = 0; nt < 8; ++nt)
#pragma unroll
                for (int r = 0; r < 4; ++r) o_acc[nt][r] *= alpha[r];

            // O += P V  (P wave-private: lgkmcnt ordering suffices, no barrier)
#pragma unroll
            for (int ks2 = 0; ks2 < 2; ++ks2) {
                bf16x8 pf = *(const bf16x8*)&Pw[lm * 72 + ks2 * 32 + q8 * 8];
#pragma unroll
                for (int nt = 0; nt < 8; ++nt) {
                    bf16x8 vf = *(const bf16x8*)&Vs[(nt * 16 + lm) * 72 + ks2 * 32 + q8 * 8];
                    o_acc[nt] = __builtin_amdgcn_mfma_f32_16x16x32_bf16(pf, vf, o_acc[nt], 0, 0, 0);
                }
            }
        }
    }

    float inv[4];
#pragma unroll
    for (int r = 0; r < 4; ++r) inv[r] = 1.f / l_i[r];
#pragma unroll
    for (int nt = 0; nt < 8; ++nt)
#pragma unroll
        for (int r = 0; r < 4; ++r) {
            int rowg = q0 + wrow + q8 * 4 + r;
            y[(size_t)(b * TT + rowg) * CC + h * HD + nt * 16 + lm] = f2bf(o_acc[nt][r] * inv[r]);
        }
}

// ---------------------------------------------------------------------------
extern "C" void kernel_launch(void* const* d_in, const int* in_sizes, int n_in,
                              void* d_out, int out_size, void* d_ws, size_t ws_size,
                              hipStream_t stream) {
    const float* x    = (const float*)d_in[0];
    const float* cosb = (const float*)d_in[1];
    const float* sinb = (const float*)d_in[2];
    const float* Wq   = (const float*)d_in[3];
    const float* bq   = (const float*)d_in[4];
    const float* Wk   = (const float*)d_in[5];
    const float* bk   = (const float*)d_in[6];
    const float* Wv   = (const float*)d_in[7];
    const float* bv   = (const float*)d_in[8];
    const float* Wo   = (const float*)d_in[9];
    float* out = (float*)d_out;

    // workspace (all bf16 as ushort):
    // xb[4096*2048] Wt[3072*2048] Wot[2048*2048] qb[4096*2048]
    // kb[4096*512] vb[4096*512] vtb[1024*2048] yb[4096*2048]  = 83.9 MB
    unsigned short* xb  = (unsigned short*)d_ws;
    unsigned short* Wt  = xb  + (size_t)MM * CC;
    unsigned short* Wot = Wt  + (size_t)3072 * 2048;
    unsigned short* qb  = Wot + (size_t)2048 * 2048;
    unsigned short* kb  = qb  + (size_t)MM * CC;
    unsigned short* vb  = kb  + (size_t)MM * (HKK * HD);
    unsigned short* vtb = vb  + (size_t)MM * (HKK * HD);
    unsigned short* ybf = vtb + (size_t)BB * HKK * HD * TT;

    cast_x_kernel<<<dim3((MM * CC) / 2048), 256, 0, stream>>>(x, xb);
    wtrans_kernel<<<dim3(32, 32, 4), 256, 0, stream>>>(Wq, Wk, Wv, Wo, Wt, Wot);
    qkv_gemm_mfma<<<dim3(3072 / 128, MM / 128), 256, 0, stream>>>(xb, Wt, bq, bk, bv, qb, kb, vb);
    rope_bf<<<dim3((MM * 20) / 4), 256, 0, stream>>>(qb, kb, cosb, sinb);
    vtrans_kernel<<<dim3(TT / 64, HD / 64, BB * HKK), 256, 0, stream>>>(vb, vtb);
    flash_mfma<<<dim3(BB * HH, TT / 128), 512, 0, stream>>>(qb, kb, vtb, ybf);
    out_gemm_mfma<<<dim3(CC / 128, MM / 128), 256, 0, stream>>>(ybf, Wot, out);
}

// Round 7
// 399.104 us; speedup vs baseline: 7.5116x; 1.0480x over previous
//
#include <hip/hip_runtime.h>
#include <math.h>

// Problem constants
#define BB 2
#define TT 2048
#define CC 2048
#define HH 16
#define HKK 4
#define HD 128
#define MM (BB*TT)          // 4096 rows

typedef short bf16x8 __attribute__((ext_vector_type(8)));
typedef float f32x4 __attribute__((ext_vector_type(4)));

#define GLOBAL_AS(p) ((const __attribute__((address_space(1))) void*)(p))
#define LDS_AS(p)    ((__attribute__((address_space(3))) void*)(p))

__device__ __forceinline__ unsigned short f2bf(float f) {
    unsigned u = __float_as_uint(f);
    u += 0x7fff + ((u >> 16) & 1);          // round-to-nearest-even
    return (unsigned short)(u >> 16);
}
__device__ __forceinline__ float bf2f(unsigned short h) {
    return __uint_as_float(((unsigned)h) << 16);
}

// ---------------------------------------------------------------------------
// cast x (f32 -> bf16), 8 elements/thread
// ---------------------------------------------------------------------------
__global__ __launch_bounds__(256) void cast_x_kernel(
    const float* __restrict__ x, unsigned short* __restrict__ xb)
{
    size_t i = ((size_t)blockIdx.x * 256 + threadIdx.x) * 8;
    float4 a = *(const float4*)&x[i];
    float4 b = *(const float4*)&x[i + 4];
    uint4 r;
    r.x = f2bf(a.x) | ((unsigned)f2bf(a.y) << 16);
    r.y = f2bf(a.z) | ((unsigned)f2bf(a.w) << 16);
    r.z = f2bf(b.x) | ((unsigned)f2bf(b.y) << 16);
    r.w = f2bf(b.z) | ((unsigned)f2bf(b.w) << 16);
    *(uint4*)&xb[i] = r;
}

// ---------------------------------------------------------------------------
// Weight transpose+cast: W[K][N] f32 -> Wt[N][K] bf16.
// ---------------------------------------------------------------------------
__global__ __launch_bounds__(256) void wtrans_kernel(
    const float* __restrict__ Wq, const float* __restrict__ Wk,
    const float* __restrict__ Wv, const float* __restrict__ Wo,
    unsigned short* __restrict__ Wt, unsigned short* __restrict__ Wot)
{
    __shared__ float tile[64][65];
    int z = blockIdx.z;
    const float* src; unsigned short* dst; int ldW, nmax, noff;
    if (z == 0)      { src = Wq; dst = Wt;  ldW = 2048; nmax = 2048; noff = 0; }
    else if (z == 1) { src = Wk; dst = Wt;  ldW = 512;  nmax = 512;  noff = 2048; }
    else if (z == 2) { src = Wv; dst = Wt;  ldW = 512;  nmax = 512;  noff = 2560; }
    else             { src = Wo; dst = Wot; ldW = 2048; nmax = 2048; noff = 0; }
    int n0 = blockIdx.y * 64;
    if (n0 >= nmax) return;
    int k0 = blockIdx.x * 64;
    int tx = threadIdx.x & 15, ty = threadIdx.x >> 4;
#pragma unroll
    for (int i = 0; i < 4; ++i) {
        int r = ty + i * 16;
        float4 v4 = *(const float4*)&src[(size_t)(k0 + r) * ldW + n0 + tx * 4];
        tile[r][tx * 4 + 0] = v4.x;
        tile[r][tx * 4 + 1] = v4.y;
        tile[r][tx * 4 + 2] = v4.z;
        tile[r][tx * 4 + 3] = v4.w;
    }
    __syncthreads();
#pragma unroll
    for (int i = 0; i < 4; ++i) {
        int r = ty + i * 16;     // n-local
        int c = tx * 4;          // k-local
        ushort4 o;
        o.x = f2bf(tile[c + 0][r]);
        o.y = f2bf(tile[c + 1][r]);
        o.z = f2bf(tile[c + 2][r]);
        o.w = f2bf(tile[c + 3][r]);
        *(ushort4*)&dst[(size_t)(noff + n0 + r) * 2048 + k0 + c] = o;
    }
}

// ---------------------------------------------------------------------------
// MFMA GEMM 128x128x64 tile, 4 waves (2x2), 16x16x32 bf16.
// Staging via global_load_lds (16B/lane); XOR-swizzled k-chunks.
// ---------------------------------------------------------------------------
__device__ __forceinline__ void gemm_core_128x128x64(
    const unsigned short* __restrict__ A, const unsigned short* __restrict__ B,
    short* As, short* Bs, int m0, int n0, f32x4 (&acc)[4][4])
{
    const int tid = threadIdx.x;
    const int lane = tid & 63;
    const int w = tid >> 6;
    const int wm = (w & 1) * 64;
    const int wn = (w >> 1) * 64;
    const int lm = lane & 15;
    const int q8 = lane >> 4;

    const int lrow = lane >> 3;            // 0..7 within an instr's 8 rows
    const int lchunk = lane & 7;           // lane's LDS chunk slot

    for (int kt = 0; kt < CC; kt += 64) {
        __syncthreads();                   // prev iter frag reads complete
#pragma unroll
        for (int jj = 0; jj < 4; ++jj) {
            int rA = w * 32 + jj * 8 + lrow;
            int cA = ((lchunk ^ (rA & 7)) << 3);
            __builtin_amdgcn_global_load_lds(
                GLOBAL_AS(&A[(size_t)(m0 + rA) * CC + kt + cA]),
                LDS_AS(&As[(w * 32 + jj * 8) * 64]), 16, 0, 0);
            __builtin_amdgcn_global_load_lds(
                GLOBAL_AS(&B[(size_t)(n0 + rA) * CC + kt + cA]),
                LDS_AS(&Bs[(w * 32 + jj * 8) * 64]), 16, 0, 0);
        }
        __syncthreads();                   // vmcnt drained -> tiles visible
#pragma unroll
        for (int ksi = 0; ksi < 2; ++ksi) {
            bf16x8 af[4], bf[4];
#pragma unroll
            for (int i = 0; i < 4; ++i) {
                int xo = (((ksi * 4 + q8) ^ (lm & 7)) << 3);
                af[i] = *(const bf16x8*)&As[(wm + i * 16 + lm) * 64 + xo];
                bf[i] = *(const bf16x8*)&Bs[(wn + i * 16 + lm) * 64 + xo];
            }
#pragma unroll
            for (int im = 0; im < 4; ++im)
#pragma unroll
                for (int in = 0; in < 4; ++in)
                    acc[im][in] = __builtin_amdgcn_mfma_f32_16x16x32_bf16(af[im], bf[in], acc[im][in], 0, 0, 0);
        }
    }
}

__global__ __launch_bounds__(256, 3) void qkv_gemm_mfma(
    const unsigned short* __restrict__ xb, const unsigned short* __restrict__ Wt,
    const float* __restrict__ bq, const float* __restrict__ bk, const float* __restrict__ bv,
    unsigned short* __restrict__ q, unsigned short* __restrict__ k, unsigned short* __restrict__ v)
{
    __shared__ __attribute__((aligned(16))) short As[128 * 64];
    __shared__ __attribute__((aligned(16))) short Bs[128 * 64];
    const int lane = threadIdx.x & 63;
    const int w = threadIdx.x >> 6;
    const int wm = (w & 1) * 64;
    const int wn = (w >> 1) * 64;
    const int m0 = blockIdx.y * 128;
    const int n0 = blockIdx.x * 128;
    const int lm = lane & 15;
    const int q8 = lane >> 4;

    f32x4 acc[4][4];
#pragma unroll
    for (int im = 0; im < 4; ++im)
#pragma unroll
        for (int in = 0; in < 4; ++in) acc[im][in] = {0.f, 0.f, 0.f, 0.f};

    gemm_core_128x128x64(xb, Wt, As, Bs, m0, n0, acc);

    unsigned short* dst; const float* bias; int ldD, off;
    if (n0 < 2048)      { dst = q; bias = bq; ldD = 2048; off = n0; }
    else if (n0 < 2560) { dst = k; bias = bk; ldD = 512;  off = n0 - 2048; }
    else                { dst = v; bias = bv; ldD = 512;  off = n0 - 2560; }

#pragma unroll
    for (int in = 0; in < 4; ++in) {
        float bias_v = bias[off + wn + in * 16 + lm];
#pragma unroll
        for (int im = 0; im < 4; ++im) {
#pragma unroll
            for (int r = 0; r < 4; ++r) {
                int row = m0 + wm + im * 16 + q8 * 4 + r;   // C/D: row = quad*4+reg
                dst[(size_t)row * ldD + off + wn + in * 16 + lm] = f2bf(acc[im][in][r] + bias_v);
            }
        }
    }
}

__global__ __launch_bounds__(256, 3) void out_gemm_mfma(
    const unsigned short* __restrict__ yb, const unsigned short* __restrict__ Wot,
    float* __restrict__ Cout)
{
    __shared__ __attribute__((aligned(16))) short As[128 * 64];
    __shared__ __attribute__((aligned(16))) short Bs[128 * 64];
    const int lane = threadIdx.x & 63;
    const int w = threadIdx.x >> 6;
    const int wm = (w & 1) * 64;
    const int wn = (w >> 1) * 64;
    const int m0 = blockIdx.y * 128;
    const int n0 = blockIdx.x * 128;
    const int lm = lane & 15;
    const int q8 = lane >> 4;

    f32x4 acc[4][4];
#pragma unroll
    for (int im = 0; im < 4; ++im)
#pragma unroll
        for (int in = 0; in < 4; ++in) acc[im][in] = {0.f, 0.f, 0.f, 0.f};

    gemm_core_128x128x64(yb, Wot, As, Bs, m0, n0, acc);

#pragma unroll
    for (int im = 0; im < 4; ++im)
#pragma unroll
        for (int in = 0; in < 4; ++in)
#pragma unroll
            for (int r = 0; r < 4; ++r) {
                int row = m0 + wm + im * 16 + q8 * 4 + r;
                Cout[(size_t)row * CC + n0 + wn + in * 16 + lm] = acc[im][in][r];
            }
}

// ---------------------------------------------------------------------------
// RoPE in place on bf16 q (16 heads) and k (4 heads).
// ---------------------------------------------------------------------------
__global__ __launch_bounds__(256) void rope_bf(
    unsigned short* __restrict__ q, unsigned short* __restrict__ k,
    const float* __restrict__ cosb, const float* __restrict__ sinb)
{
    int slot = blockIdx.x * 4 + (threadIdx.x >> 6);  // 0 .. MM*20-1
    int d = threadIdx.x & 63;
    int row = slot / 20;
    int s = slot - row * 20;
    unsigned short* p = (s < 16) ? (q + (size_t)row * CC + s * HD)
                                 : (k + (size_t)row * (HKK * HD) + (s - 16) * HD);
    float c1 = cosb[row * HD + d],      s1 = sinb[row * HD + d];
    float c2 = cosb[row * HD + 64 + d], s2 = sinb[row * HD + 64 + d];
    float x1 = bf2f(p[d]);
    float x2 = bf2f(p[d + 64]);
    p[d]      = f2bf(x1 * c1 - x2 * s1);
    p[d + 64] = f2bf(x2 * c2 + x1 * s2);
}

// ---------------------------------------------------------------------------
// V transpose: v[b][t][g*128+d] bf16 -> vt[(b*4+g)*128+d][t] bf16
// ---------------------------------------------------------------------------
__global__ __launch_bounds__(256) void vtrans_kernel(
    const unsigned short* __restrict__ v, unsigned short* __restrict__ vt)
{
    __shared__ unsigned short tile[64][68];
    int bg = blockIdx.z;           // b*4+g
    int b = bg >> 2, g = bg & 3;
    int t0 = blockIdx.x * 64;
    int d0 = blockIdx.y * 64;
    int tx = threadIdx.x & 15, ty = threadIdx.x >> 4;
#pragma unroll
    for (int i = 0; i < 4; ++i) {
        int r = ty + i * 16;
        ushort4 v4 = *(const ushort4*)&v[(size_t)(b * TT + t0 + r) * (HKK * HD) + g * HD + d0 + tx * 4];
        tile[r][tx * 4 + 0] = v4.x;
        tile[r][tx * 4 + 1] = v4.y;
        tile[r][tx * 4 + 2] = v4.z;
        tile[r][tx * 4 + 3] = v4.w;
    }
    __syncthreads();
#pragma unroll
    for (int i = 0; i < 4; ++i) {
        int r = ty + i * 16;   // d-local
        int c = tx * 4;        // t-local
        ushort4 o;
        o.x = tile[c + 0][r];
        o.y = tile[c + 1][r];
        o.z = tile[c + 2][r];
        o.w = tile[c + 3][r];
        *(ushort4*)&vt[(size_t)(bg * HD + d0 + r) * TT + t0 + c] = o;
    }
}

// ---------------------------------------------------------------------------
// MFMA flash attention, BR=128, 512 threads (8 waves); wave w owns 16 q-rows
// (q0 + w*16 + lm).  BC=64.  S computed TRANSPOSED (S^T = K·Q^T) so the
// score C-layout puts the q-row in lm: softmax state (m,l) is one scalar
// per lane, max reduce is 2 shuffles, l is a per-lane partial reduced once
// at the end, P packs into 4 b64 writes in the PV A-operand layout.
// Diagonal-tile mask: token_local > (w&3)*16 + lm  (tile index jdiag
// absorbs w>>2; NOTE the &3 — w*16 here was the round-6 bug).
// exp in exp2 domain (log2e folded into Q scale).
// ---------------------------------------------------------------------------
__global__ __launch_bounds__(512, 4) void flash_mfma(
    const unsigned short* __restrict__ q, const unsigned short* __restrict__ k,
    const unsigned short* __restrict__ vt, unsigned short* __restrict__ y)
{
    __shared__ __attribute__((aligned(16))) short Ks[64 * 136];    // 17408 B
    __shared__ __attribute__((aligned(16))) short Vs[128 * 72];    // 18432 B
    __shared__ __attribute__((aligned(16))) short Ps[8 * 16 * 72]; // 18432 B

    const int tid = threadIdx.x;
    const int lane = tid & 63;
    const int w = tid >> 6;               // 0..7
    const int lm = lane & 15;
    const int q8 = lane >> 4;
    const int bh = blockIdx.x;            // 0..31
    const int b = bh >> 4, h = bh & 15, g = h >> 2;
    const int yb_ = blockIdx.y;           // 0..15
    const int qi = (yb_ < 8) ? (15 - yb_) : (yb_ - 8);   // pair long+short
    const int q0 = qi * 128;
    const int wrow = w * 16;
    const int jdiag = 2 * qi + (w >> 2);  // this wave's diagonal tile
    const int jmax = 2 * qi + 1;
    // 1/sqrt(128) * log2(e): exp computed in exp2 domain
    const float scale = 0.08838834764831845f * 1.44269504088896340736f;

    // Q fragments, pre-scaled.  B-operand of S^T = K·Q^T.
    bf16x8 qf[4];
#pragma unroll
    for (int ks = 0; ks < 4; ++ks) {
        bf16x8 t = *(const bf16x8*)&q[(size_t)(b * TT + q0 + wrow + lm) * CC
                                      + h * HD + ks * 32 + q8 * 8];
#pragma unroll
        for (int e = 0; e < 8; ++e)
            t[e] = (short)f2bf(bf2f((unsigned short)t[e]) * scale);
        qf[ks] = t;
    }

    f32x4 o_acc[8];
#pragma unroll
    for (int nt = 0; nt < 8; ++nt) o_acc[nt] = {0.f, 0.f, 0.f, 0.f};
    float m_i = -1e30f;                   // row lm's running max (exp2 domain)
    float l_i = 0.f;                      // per-lane PARTIAL row sum

    // staging geometry: 1024 16B-chunks each for K and V over 512 threads
    int ktok[2], ke8[2], vd[2], vt8[2];
#pragma unroll
    for (int i = 0; i < 2; ++i) {
        int f = tid + i * 512;
        ktok[i] = f >> 4; ke8[i] = (f & 15) * 8;
        vd[i]   = f >> 3; vt8[i] = (f & 7) * 8;
    }
    const unsigned short* kbase = k + (size_t)(b * TT) * (HKK * HD) + g * HD;
    const unsigned short* vbase = vt + (size_t)((b * 4 + g) * HD) * TT;

    uint4 kreg[2], vreg[2];
#pragma unroll
    for (int i = 0; i < 2; ++i) {
        kreg[i] = *(const uint4*)&kbase[(size_t)ktok[i] * (HKK * HD) + ke8[i]];
        vreg[i] = *(const uint4*)&vbase[(size_t)vd[i] * TT + vt8[i]];
    }

    short* Pw = Ps + w * 16 * 72;
    const int mrow = (w & 3) * 16 + lm;   // diagonal-tile row offset (the fix)

    for (int j = 0; j <= jmax; ++j) {
        __syncthreads();                 // prev iter's K/V LDS reads complete
#pragma unroll
        for (int i = 0; i < 2; ++i) {
            *(uint4*)&Ks[ktok[i] * 136 + ke8[i]] = kreg[i];
            *(uint4*)&Vs[vd[i] * 72 + vt8[i]]    = vreg[i];
        }
        __syncthreads();                 // tiles visible
        if (j < jmax) {                  // prefetch next tile (uniform branch)
#pragma unroll
            for (int i = 0; i < 2; ++i) {
                kreg[i] = *(const uint4*)&kbase[(size_t)((j + 1) * 64 + ktok[i]) * (HKK * HD) + ke8[i]];
                vreg[i] = *(const uint4*)&vbase[(size_t)vd[i] * TT + (j + 1) * 64 + vt8[i]];
            }
        }

        if (j <= jdiag) {
            // S^T = K·Q^T : A = K token-tile (m=token), B = Q^T (n=qrow)
            // C-layout: col=lm -> qrow, row=q8*4+r -> token ct*16+q8*4+r
            f32x4 sacc[4];
#pragma unroll
            for (int ct = 0; ct < 4; ++ct) {
                sacc[ct] = {0.f, 0.f, 0.f, 0.f};
#pragma unroll
                for (int ks = 0; ks < 4; ++ks) {
                    bf16x8 kf = *(const bf16x8*)&Ks[(ct * 16 + lm) * 136 + ks * 32 + q8 * 8];
                    sacc[ct] = __builtin_amdgcn_mfma_f32_16x16x32_bf16(kf, qf[ks], sacc[ct], 0, 0, 0);
                }
            }
            if (j == jdiag) {            // causal mask (only diagonal tile)
#pragma unroll
                for (int ct = 0; ct < 4; ++ct)
#pragma unroll
                    for (int r = 0; r < 4; ++r)
                        if (ct * 16 + q8 * 4 + r > mrow) sacc[ct][r] = -1e30f;
            }
            // row max: 15 in-lane + 2 cross-lane (q8 groups of row lm)
            float tmax = fmaxf(
                fmaxf(fmaxf(fmaxf(sacc[0][0], sacc[0][1]), fmaxf(sacc[0][2], sacc[0][3])),
                      fmaxf(fmaxf(sacc[1][0], sacc[1][1]), fmaxf(sacc[1][2], sacc[1][3]))),
                fmaxf(fmaxf(fmaxf(sacc[2][0], sacc[2][1]), fmaxf(sacc[2][2], sacc[2][3])),
                      fmaxf(fmaxf(sacc[3][0], sacc[3][1]), fmaxf(sacc[3][2], sacc[3][3]))));
            tmax = fmaxf(tmax, __shfl_xor(tmax, 16));
            tmax = fmaxf(tmax, __shfl_xor(tmax, 32));
            float m_new = fmaxf(m_i, tmax);
            float alpha = exp2f(m_i - m_new);
            m_i = m_new;

            float ps = 0.f;
#pragma unroll
            for (int ct = 0; ct < 4; ++ct) {
                ushort4 pp;
                float p0 = exp2f(sacc[ct][0] - m_new);
                float p1 = exp2f(sacc[ct][1] - m_new);
                float p2 = exp2f(sacc[ct][2] - m_new);
                float p3 = exp2f(sacc[ct][3] - m_new);
                ps += (p0 + p1) + (p2 + p3);
                pp.x = f2bf(p0); pp.y = f2bf(p1); pp.z = f2bf(p2); pp.w = f2bf(p3);
                // P[qrow=lm][token = ct*16 + q8*4 + 0..3]  (8B aligned)
                *(ushort4*)&Pw[lm * 72 + ct * 16 + q8 * 4] = pp;
            }
            l_i = l_i * alpha + ps;      // per-lane partial; alpha row-uniform

            // broadcast alpha to o_acc rows (row = q8*4+r -> lane q8*4+r)
            float a0 = __shfl(alpha, q8 * 4 + 0);
            float a1 = __shfl(alpha, q8 * 4 + 1);
            float a2 = __shfl(alpha, q8 * 4 + 2);
            float a3 = __shfl(alpha, q8 * 4 + 3);
#pragma unroll
            for (int nt = 0; nt < 8; ++nt) {
                o_acc[nt][0] *= a0;
                o_acc[nt][1] *= a1;
                o_acc[nt][2] *= a2;
                o_acc[nt][3] *= a3;
            }

            // O += P·V  (A = P[qrow][tok] from Ps, B = V[tok][d] from Vs=V^T)
#pragma unroll
            for (int ks2 = 0; ks2 < 2; ++ks2) {
                bf16x8 pf = *(const bf16x8*)&Pw[lm * 72 + ks2 * 32 + q8 * 8];
#pragma unroll
                for (int nt = 0; nt < 8; ++nt) {
                    bf16x8 vf = *(const bf16x8*)&Vs[(nt * 16 + lm) * 72 + ks2 * 32 + q8 * 8];
                    o_acc[nt] = __builtin_amdgcn_mfma_f32_16x16x32_bf16(pf, vf, o_acc[nt], 0, 0, 0);
                }
            }
        }
    }

    // finalize l (row lm): sum partials over the 4 q8 groups
    float lf = l_i;
    lf += __shfl_xor(lf, 16);
    lf += __shfl_xor(lf, 32);
    // o_acc rows are q8*4+r: fetch their row sums
    float inv[4];
#pragma unroll
    for (int r = 0; r < 4; ++r) inv[r] = 1.f / __shfl(lf, q8 * 4 + r);
#pragma unroll
    for (int nt = 0; nt < 8; ++nt)
#pragma unroll
        for (int r = 0; r < 4; ++r) {
            int rowg = q0 + wrow + q8 * 4 + r;
            y[(size_t)(b * TT + rowg) * CC + h * HD + nt * 16 + lm] = f2bf(o_acc[nt][r] * inv[r]);
        }
}

// ---------------------------------------------------------------------------
extern "C" void kernel_launch(void* const* d_in, const int* in_sizes, int n_in,
                              void* d_out, int out_size, void* d_ws, size_t ws_size,
                              hipStream_t stream) {
    const float* x    = (const float*)d_in[0];
    const float* cosb = (const float*)d_in[1];
    const float* sinb = (const float*)d_in[2];
    const float* Wq   = (const float*)d_in[3];
    const float* bq   = (const float*)d_in[4];
    const float* Wk   = (const float*)d_in[5];
    const float* bk   = (const float*)d_in[6];
    const float* Wv   = (const float*)d_in[7];
    const float* bv   = (const float*)d_in[8];
    const float* Wo   = (const float*)d_in[9];
    float* out = (float*)d_out;

    // workspace (all bf16 as ushort):
    // xb[4096*2048] Wt[3072*2048] Wot[2048*2048] qb[4096*2048]
    // kb[4096*512] vb[4096*512] vtb[1024*2048] yb[4096*2048]  = 83.9 MB
    unsigned short* xb  = (unsigned short*)d_ws;
    unsigned short* Wt  = xb  + (size_t)MM * CC;
    unsigned short* Wot = Wt  + (size_t)3072 * 2048;
    unsigned short* qb  = Wot + (size_t)2048 * 2048;
    unsigned short* kb  = qb  + (size_t)MM * CC;
    unsigned short* vb  = kb  + (size_t)MM * (HKK * HD);
    unsigned short* vtb = vb  + (size_t)MM * (HKK * HD);
    unsigned short* ybf = vtb + (size_t)BB * HKK * HD * TT;

    cast_x_kernel<<<dim3((MM * CC) / 2048), 256, 0, stream>>>(x, xb);
    wtrans_kernel<<<dim3(32, 32, 4), 256, 0, stream>>>(Wq, Wk, Wv, Wo, Wt, Wot);
    qkv_gemm_mfma<<<dim3(3072 / 128, MM / 128), 256, 0, stream>>>(xb, Wt, bq, bk, bv, qb, kb, vb);
    rope_bf<<<dim3((MM * 20) / 4), 256, 0, stream>>>(qb, kb, cosb, sinb);
    vtrans_kernel<<<dim3(TT / 64, HD / 64, BB * HKK), 256, 0, stream>>>(vb, vtb);
    flash_mfma<<<dim3(BB * HH, TT / 128), 512, 0, stream>>>(qb, kb, vtb, ybf);
    out_gemm_mfma<<<dim3(CC / 128, MM / 128), 256, 0, stream>>>(ybf, Wot, out);
}

// Round 8
// 374.895 us; speedup vs baseline: 7.9967x; 1.0646x over previous
//
#include <hip/hip_runtime.h>
#include <math.h>

// Problem constants
#define BB 2
#define TT 2048
#define CC 2048
#define HH 16
#define HKK 4
#define HD 128
#define MM (BB*TT)          // 4096 rows

typedef short bf16x8 __attribute__((ext_vector_type(8)));
typedef float f32x4 __attribute__((ext_vector_type(4)));

#define GLOBAL_AS(p) ((const __attribute__((address_space(1))) void*)(p))
#define LDS_AS(p)    ((__attribute__((address_space(3))) void*)(p))

__device__ __forceinline__ unsigned short f2bf(float f) {
    unsigned u = __float_as_uint(f);
    u += 0x7fff + ((u >> 16) & 1);          // round-to-nearest-even
    return (unsigned short)(u >> 16);
}
__device__ __forceinline__ float bf2f(unsigned short h) {
    return __uint_as_float(((unsigned)h) << 16);
}

// softmax scale 1/sqrt(128) * log2(e), folded into q at projection time
#define QSCALE (0.08838834764831845f * 1.44269504088896340736f)

// ---------------------------------------------------------------------------
// cast x (f32 -> bf16), 8 elements/thread
// ---------------------------------------------------------------------------
__global__ __launch_bounds__(256) void cast_x_kernel(
    const float* __restrict__ x, unsigned short* __restrict__ xb)
{
    size_t i = ((size_t)blockIdx.x * 256 + threadIdx.x) * 8;
    float4 a = *(const float4*)&x[i];
    float4 b = *(const float4*)&x[i + 4];
    uint4 r;
    r.x = f2bf(a.x) | ((unsigned)f2bf(a.y) << 16);
    r.y = f2bf(a.z) | ((unsigned)f2bf(a.w) << 16);
    r.z = f2bf(b.x) | ((unsigned)f2bf(b.y) << 16);
    r.w = f2bf(b.z) | ((unsigned)f2bf(b.w) << 16);
    *(uint4*)&xb[i] = r;
}

// ---------------------------------------------------------------------------
// Weight transpose+cast: W[K][N] f32 -> Wt[N][K] bf16.
// ---------------------------------------------------------------------------
__global__ __launch_bounds__(256) void wtrans_kernel(
    const float* __restrict__ Wq, const float* __restrict__ Wk,
    const float* __restrict__ Wv, const float* __restrict__ Wo,
    unsigned short* __restrict__ Wt, unsigned short* __restrict__ Wot)
{
    __shared__ float tile[64][65];
    int z = blockIdx.z;
    const float* src; unsigned short* dst; int ldW, nmax, noff;
    if (z == 0)      { src = Wq; dst = Wt;  ldW = 2048; nmax = 2048; noff = 0; }
    else if (z == 1) { src = Wk; dst = Wt;  ldW = 512;  nmax = 512;  noff = 2048; }
    else if (z == 2) { src = Wv; dst = Wt;  ldW = 512;  nmax = 512;  noff = 2560; }
    else             { src = Wo; dst = Wot; ldW = 2048; nmax = 2048; noff = 0; }
    int n0 = blockIdx.y * 64;
    if (n0 >= nmax) return;
    int k0 = blockIdx.x * 64;
    int tx = threadIdx.x & 15, ty = threadIdx.x >> 4;
#pragma unroll
    for (int i = 0; i < 4; ++i) {
        int r = ty + i * 16;
        float4 v4 = *(const float4*)&src[(size_t)(k0 + r) * ldW + n0 + tx * 4];
        tile[r][tx * 4 + 0] = v4.x;
        tile[r][tx * 4 + 1] = v4.y;
        tile[r][tx * 4 + 2] = v4.z;
        tile[r][tx * 4 + 3] = v4.w;
    }
    __syncthreads();
#pragma unroll
    for (int i = 0; i < 4; ++i) {
        int r = ty + i * 16;     // n-local
        int c = tx * 4;          // k-local
        ushort4 o;
        o.x = f2bf(tile[c + 0][r]);
        o.y = f2bf(tile[c + 1][r]);
        o.z = f2bf(tile[c + 2][r]);
        o.w = f2bf(tile[c + 3][r]);
        *(ushort4*)&dst[(size_t)(noff + n0 + r) * 2048 + k0 + c] = o;
    }
}

// ---------------------------------------------------------------------------
// MFMA GEMM core 128x128x64, 4 waves, 16x16x32 bf16, global_load_lds staging,
// XOR-swizzled k-chunks.  mrow/nrow give each wave's 4 m/n tile bases.
// ---------------------------------------------------------------------------
__device__ __forceinline__ void gemm_core_128x128x64(
    const unsigned short* __restrict__ A, const unsigned short* __restrict__ B,
    short* As, short* Bs, int m0, int n0,
    const int* mrow, const int* nrow, f32x4 (&acc)[4][4])
{
    const int tid = threadIdx.x;
    const int lane = tid & 63;
    const int w = tid >> 6;
    const int lm = lane & 15;
    const int q8 = lane >> 4;
    const int lrow = lane >> 3;            // 0..7 within an instr's 8 rows
    const int lchunk = lane & 7;           // lane's LDS chunk slot

    for (int kt = 0; kt < CC; kt += 64) {
        __syncthreads();                   // prev iter frag reads complete
#pragma unroll
        for (int jj = 0; jj < 4; ++jj) {
            int rA = w * 32 + jj * 8 + lrow;
            int cA = ((lchunk ^ (rA & 7)) << 3);
            __builtin_amdgcn_global_load_lds(
                GLOBAL_AS(&A[(size_t)(m0 + rA) * CC + kt + cA]),
                LDS_AS(&As[(w * 32 + jj * 8) * 64]), 16, 0, 0);
            __builtin_amdgcn_global_load_lds(
                GLOBAL_AS(&B[(size_t)(n0 + rA) * CC + kt + cA]),
                LDS_AS(&Bs[(w * 32 + jj * 8) * 64]), 16, 0, 0);
        }
        __syncthreads();                   // vmcnt drained -> tiles visible
#pragma unroll
        for (int ksi = 0; ksi < 2; ++ksi) {
            bf16x8 af[4], bfr[4];
#pragma unroll
            for (int i = 0; i < 4; ++i) {
                int xo = (((ksi * 4 + q8) ^ (lm & 7)) << 3);
                af[i]  = *(const bf16x8*)&As[(mrow[i] + lm) * 64 + xo];
                bfr[i] = *(const bf16x8*)&Bs[(nrow[i] + lm) * 64 + xo];
            }
#pragma unroll
            for (int im = 0; im < 4; ++im)
#pragma unroll
                for (int in = 0; in < 4; ++in)
                    acc[im][in] = __builtin_amdgcn_mfma_f32_16x16x32_bf16(af[im], bfr[in], acc[im][in], 0, 0, 0);
        }
    }
}

// ---------------------------------------------------------------------------
// QKV GEMM with fused bias + RoPE + q-scale.  Each 128-col block is exactly
// one head (HD=128).  Wave n-tiles remapped to {w1*32+(in&1)*16+(in>>1)*64}
// so d and d^64 are in the SAME lane at in^2 -> in-register RoPE.
// ---------------------------------------------------------------------------
__global__ __launch_bounds__(256, 3) void qkv_gemm_mfma(
    const unsigned short* __restrict__ xb, const unsigned short* __restrict__ Wt,
    const float* __restrict__ bq, const float* __restrict__ bk, const float* __restrict__ bv,
    const float* __restrict__ cosb, const float* __restrict__ sinb,
    unsigned short* __restrict__ q, unsigned short* __restrict__ k, unsigned short* __restrict__ v)
{
    __shared__ __attribute__((aligned(16))) short As[128 * 64];
    __shared__ __attribute__((aligned(16))) short Bs[128 * 64];
    const int lane = threadIdx.x & 63;
    const int w = threadIdx.x >> 6;
    const int w1 = w >> 1;
    const int m0 = blockIdx.y * 128;
    const int n0 = blockIdx.x * 128;
    const int lm = lane & 15;
    const int q8 = lane >> 4;

    int mrow[4], nrow[4];
#pragma unroll
    for (int i = 0; i < 4; ++i) {
        mrow[i] = (w & 1) * 64 + i * 16;
        nrow[i] = w1 * 32 + (i & 1) * 16 + (i >> 1) * 64;   // d and d^64 at in^2
    }

    f32x4 acc[4][4];
#pragma unroll
    for (int im = 0; im < 4; ++im)
#pragma unroll
        for (int in = 0; in < 4; ++in) acc[im][in] = {0.f, 0.f, 0.f, 0.f};

    gemm_core_128x128x64(xb, Wt, As, Bs, m0, n0, mrow, nrow, acc);

    unsigned short* dst; const float* bias; int ldD, off, mode;
    if (n0 < 2048)      { dst = q; bias = bq; ldD = 2048; off = n0;        mode = 0; }
    else if (n0 < 2560) { dst = k; bias = bk; ldD = 512;  off = n0 - 2048; mode = 1; }
    else                { dst = v; bias = bv; ldD = 512;  off = n0 - 2560; mode = 2; }

    float bv_[4];
#pragma unroll
    for (int in = 0; in < 4; ++in) bv_[in] = bias[off + nrow[in] + lm];

#pragma unroll
    for (int im = 0; im < 4; ++im) {
        int rowbase = m0 + mrow[im] + q8 * 4;
        float t[4][4];                      // [in][r], biased pre-rope values
#pragma unroll
        for (int in = 0; in < 4; ++in)
#pragma unroll
            for (int r = 0; r < 4; ++r) t[in][r] = acc[im][in][r] + bv_[in];
        if (mode < 2) {                     // rope (q and k)
#pragma unroll
            for (int in = 0; in < 4; ++in) {
                int d = nrow[in] + lm;
                float sgn = (in < 2) ? -1.f : 1.f;   // d<64 <=> in<2
#pragma unroll
                for (int r = 0; r < 4; ++r) {
                    int row = rowbase + r;
                    float c = cosb[row * HD + d];
                    float s = sinb[row * HD + d];
                    float o = c * t[in][r] + sgn * s * t[in ^ 2][r];
                    if (mode == 0) o *= QSCALE;
                    dst[(size_t)row * ldD + off + d] = f2bf(o);
                }
            }
        } else {                            // v: bias only
#pragma unroll
            for (int in = 0; in < 4; ++in)
#pragma unroll
                for (int r = 0; r < 4; ++r)
                    dst[(size_t)(rowbase + r) * ldD + off + nrow[in] + lm] = f2bf(t[in][r]);
        }
    }
}

__global__ __launch_bounds__(256, 3) void out_gemm_mfma(
    const unsigned short* __restrict__ yb, const unsigned short* __restrict__ Wot,
    float* __restrict__ Cout)
{
    __shared__ __attribute__((aligned(16))) short As[128 * 64];
    __shared__ __attribute__((aligned(16))) short Bs[128 * 64];
    const int lane = threadIdx.x & 63;
    const int w = threadIdx.x >> 6;
    const int m0 = blockIdx.y * 128;
    const int n0 = blockIdx.x * 128;
    const int lm = lane & 15;
    const int q8 = lane >> 4;

    int mrow[4], nrow[4];
#pragma unroll
    for (int i = 0; i < 4; ++i) {
        mrow[i] = (w & 1) * 64 + i * 16;
        nrow[i] = (w >> 1) * 64 + i * 16;
    }

    f32x4 acc[4][4];
#pragma unroll
    for (int im = 0; im < 4; ++im)
#pragma unroll
        for (int in = 0; in < 4; ++in) acc[im][in] = {0.f, 0.f, 0.f, 0.f};

    gemm_core_128x128x64(yb, Wot, As, Bs, m0, n0, mrow, nrow, acc);

#pragma unroll
    for (int im = 0; im < 4; ++im)
#pragma unroll
        for (int in = 0; in < 4; ++in)
#pragma unroll
            for (int r = 0; r < 4; ++r) {
                int row = m0 + mrow[im] + q8 * 4 + r;
                Cout[(size_t)row * CC + n0 + nrow[in] + lm] = acc[im][in][r];
            }
}

// ---------------------------------------------------------------------------
// V transpose: v[b][t][g*128+d] bf16 -> vt[(b*4+g)*128+d][t] bf16
// ---------------------------------------------------------------------------
__global__ __launch_bounds__(256) void vtrans_kernel(
    const unsigned short* __restrict__ v, unsigned short* __restrict__ vt)
{
    __shared__ unsigned short tile[64][68];
    int bg = blockIdx.z;           // b*4+g
    int b = bg >> 2, g = bg & 3;
    int t0 = blockIdx.x * 64;
    int d0 = blockIdx.y * 64;
    int tx = threadIdx.x & 15, ty = threadIdx.x >> 4;
#pragma unroll
    for (int i = 0; i < 4; ++i) {
        int r = ty + i * 16;
        ushort4 v4 = *(const ushort4*)&v[(size_t)(b * TT + t0 + r) * (HKK * HD) + g * HD + d0 + tx * 4];
        tile[r][tx * 4 + 0] = v4.x;
        tile[r][tx * 4 + 1] = v4.y;
        tile[r][tx * 4 + 2] = v4.z;
        tile[r][tx * 4 + 3] = v4.w;
    }
    __syncthreads();
#pragma unroll
    for (int i = 0; i < 4; ++i) {
        int r = ty + i * 16;   // d-local
        int c = tx * 4;        // t-local
        ushort4 o;
        o.x = tile[c + 0][r];
        o.y = tile[c + 1][r];
        o.z = tile[c + 2][r];
        o.w = tile[c + 3][r];
        *(ushort4*)&vt[(size_t)(bg * HD + d0 + r) * TT + t0 + c] = o;
    }
}

// ---------------------------------------------------------------------------
// MFMA flash attention, BR=128, 512 threads (8 waves); wave w owns 16 q-rows.
// BC=64.  S computed transposed (S^T = K·Q^T): softmax state is per-lane
// scalar, 2 shuffles for max, per-lane partial l.  q is pre-scaled (QSCALE,
// exp2 domain) and pre-roped by qkv_gemm.  Epilogue stages O through LDS
// (reusing Ks/Vs space) for coalesced dwordx4 y-stores — fixes the ~6x
// write amplification of scalar b16 stores (r7: WRITE_SIZE 104 MB vs 16).
// ---------------------------------------------------------------------------
__global__ __launch_bounds__(512, 4) void flash_mfma(
    const unsigned short* __restrict__ q, const unsigned short* __restrict__ k,
    const unsigned short* __restrict__ vt, unsigned short* __restrict__ y)
{
    // Ks 64x136 | Vs 128x72 | Ps 8x16x72   (27136 shorts = 54272 B)
    __shared__ __attribute__((aligned(16))) short SM[27136];
    short* Ks = SM;                 // 8704 shorts
    short* Vs = SM + 8704;          // 9216 shorts
    short* Ps = SM + 17920;         // 9216 shorts

    const int tid = threadIdx.x;
    const int lane = tid & 63;
    const int w = tid >> 6;               // 0..7
    const int lm = lane & 15;
    const int q8 = lane >> 4;
    const int bh = blockIdx.x;            // 0..31
    const int b = bh >> 4, h = bh & 15, g = h >> 2;
    const int yb_ = blockIdx.y;           // 0..15
    const int qi = (yb_ < 8) ? (15 - yb_) : (yb_ - 8);   // pair long+short
    const int q0 = qi * 128;
    const int wrow = w * 16;
    const int jdiag = 2 * qi + (w >> 2);  // this wave's diagonal tile
    const int jmax = 2 * qi + 1;

    // Q fragments (pre-scaled + roped by qkv_gemm).  B-operand of S^T = K·Q^T.
    bf16x8 qf[4];
#pragma unroll
    for (int ks = 0; ks < 4; ++ks)
        qf[ks] = *(const bf16x8*)&q[(size_t)(b * TT + q0 + wrow + lm) * CC
                                    + h * HD + ks * 32 + q8 * 8];

    f32x4 o_acc[8];
#pragma unroll
    for (int nt = 0; nt < 8; ++nt) o_acc[nt] = {0.f, 0.f, 0.f, 0.f};
    float m_i = -1e30f;                   // row lm's running max (exp2 domain)
    float l_i = 0.f;                      // per-lane PARTIAL row sum

    // staging geometry: 1024 16B-chunks each for K and V over 512 threads
    int ktok[2], ke8[2], vd[2], vt8[2];
#pragma unroll
    for (int i = 0; i < 2; ++i) {
        int f = tid + i * 512;
        ktok[i] = f >> 4; ke8[i] = (f & 15) * 8;
        vd[i]   = f >> 3; vt8[i] = (f & 7) * 8;
    }
    const unsigned short* kbase = k + (size_t)(b * TT) * (HKK * HD) + g * HD;
    const unsigned short* vbase = vt + (size_t)((b * 4 + g) * HD) * TT;

    uint4 kreg[2], vreg[2];
#pragma unroll
    for (int i = 0; i < 2; ++i) {
        kreg[i] = *(const uint4*)&kbase[(size_t)ktok[i] * (HKK * HD) + ke8[i]];
        vreg[i] = *(const uint4*)&vbase[(size_t)vd[i] * TT + vt8[i]];
    }

    short* Pw = Ps + w * 16 * 72;
    const int mrow = (w & 3) * 16 + lm;   // diagonal-tile row offset

    for (int j = 0; j <= jmax; ++j) {
        __syncthreads();                 // prev iter's K/V LDS reads complete
#pragma unroll
        for (int i = 0; i < 2; ++i) {
            *(uint4*)&Ks[ktok[i] * 136 + ke8[i]] = kreg[i];
            *(uint4*)&Vs[vd[i] * 72 + vt8[i]]    = vreg[i];
        }
        __syncthreads();                 // tiles visible
        if (j < jmax) {                  // prefetch next tile (uniform branch)
#pragma unroll
            for (int i = 0; i < 2; ++i) {
                kreg[i] = *(const uint4*)&kbase[(size_t)((j + 1) * 64 + ktok[i]) * (HKK * HD) + ke8[i]];
                vreg[i] = *(const uint4*)&vbase[(size_t)vd[i] * TT + (j + 1) * 64 + vt8[i]];
            }
        }

        if (j <= jdiag) {
            // S^T = K·Q^T : C-layout col=lm -> qrow, row=q8*4+r -> token
            f32x4 sacc[4];
#pragma unroll
            for (int ct = 0; ct < 4; ++ct) {
                sacc[ct] = {0.f, 0.f, 0.f, 0.f};
#pragma unroll
                for (int ks = 0; ks < 4; ++ks) {
                    bf16x8 kf = *(const bf16x8*)&Ks[(ct * 16 + lm) * 136 + ks * 32 + q8 * 8];
                    sacc[ct] = __builtin_amdgcn_mfma_f32_16x16x32_bf16(kf, qf[ks], sacc[ct], 0, 0, 0);
                }
            }
            if (j == jdiag) {            // causal mask (only diagonal tile)
#pragma unroll
                for (int ct = 0; ct < 4; ++ct)
#pragma unroll
                    for (int r = 0; r < 4; ++r)
                        if (ct * 16 + q8 * 4 + r > mrow) sacc[ct][r] = -1e30f;
            }
            // row max: 15 in-lane + 2 cross-lane
            float tmax = fmaxf(
                fmaxf(fmaxf(fmaxf(sacc[0][0], sacc[0][1]), fmaxf(sacc[0][2], sacc[0][3])),
                      fmaxf(fmaxf(sacc[1][0], sacc[1][1]), fmaxf(sacc[1][2], sacc[1][3]))),
                fmaxf(fmaxf(fmaxf(sacc[2][0], sacc[2][1]), fmaxf(sacc[2][2], sacc[2][3])),
                      fmaxf(fmaxf(sacc[3][0], sacc[3][1]), fmaxf(sacc[3][2], sacc[3][3]))));
            tmax = fmaxf(tmax, __shfl_xor(tmax, 16));
            tmax = fmaxf(tmax, __shfl_xor(tmax, 32));
            float m_new = fmaxf(m_i, tmax);
            float alpha = exp2f(m_i - m_new);
            m_i = m_new;

            float ps = 0.f;
#pragma unroll
            for (int ct = 0; ct < 4; ++ct) {
                ushort4 pp;
                float p0 = exp2f(sacc[ct][0] - m_new);
                float p1 = exp2f(sacc[ct][1] - m_new);
                float p2 = exp2f(sacc[ct][2] - m_new);
                float p3 = exp2f(sacc[ct][3] - m_new);
                ps += (p0 + p1) + (p2 + p3);
                pp.x = f2bf(p0); pp.y = f2bf(p1); pp.z = f2bf(p2); pp.w = f2bf(p3);
                *(ushort4*)&Pw[lm * 72 + ct * 16 + q8 * 4] = pp;
            }
            l_i = l_i * alpha + ps;      // per-lane partial; alpha row-uniform

            float a0 = __shfl(alpha, q8 * 4 + 0);
            float a1 = __shfl(alpha, q8 * 4 + 1);
            float a2 = __shfl(alpha, q8 * 4 + 2);
            float a3 = __shfl(alpha, q8 * 4 + 3);
#pragma unroll
            for (int nt = 0; nt < 8; ++nt) {
                o_acc[nt][0] *= a0;
                o_acc[nt][1] *= a1;
                o_acc[nt][2] *= a2;
                o_acc[nt][3] *= a3;
            }

            // O += P·V
#pragma unroll
            for (int ks2 = 0; ks2 < 2; ++ks2) {
                bf16x8 pf = *(const bf16x8*)&Pw[lm * 72 + ks2 * 32 + q8 * 8];
#pragma unroll
                for (int nt = 0; nt < 8; ++nt) {
                    bf16x8 vf = *(const bf16x8*)&Vs[(nt * 16 + lm) * 72 + ks2 * 32 + q8 * 8];
                    o_acc[nt] = __builtin_amdgcn_mfma_f32_16x16x32_bf16(pf, vf, o_acc[nt], 0, 0, 0);
                }
            }
        }
    }

    // finalize l: sum partials over the 4 q8 groups, fetch per-o_acc-row
    float lf = l_i;
    lf += __shfl_xor(lf, 16);
    lf += __shfl_xor(lf, 32);
    float inv[4];
#pragma unroll
    for (int r = 0; r < 4; ++r) inv[r] = 1.f / __shfl(lf, q8 * 4 + r);

    // Epilogue: stage O in LDS (128 rows x stride 136, over Ks+Vs space),
    // read back b128, store coalesced dwordx4.
    __syncthreads();                       // all waves done with Ks/Vs/Ps
    short* Es = SM;                        // 128*136 = 17408 shorts
#pragma unroll
    for (int nt = 0; nt < 8; ++nt)
#pragma unroll
        for (int r = 0; r < 4; ++r)
            Es[(w * 16 + q8 * 4 + r) * 136 + nt * 16 + lm] = (short)f2bf(o_acc[nt][r] * inv[r]);
    __syncthreads();
#pragma unroll
    for (int i = 0; i < 4; ++i) {
        int f = tid + i * 512;             // 0..2047
        int row = f >> 4, ch = f & 15;
        uint4 t = *(const uint4*)&Es[row * 136 + ch * 8];
        *(uint4*)&y[(size_t)(b * TT + q0 + row) * CC + h * HD + ch * 8] = t;
    }
}

// ---------------------------------------------------------------------------
extern "C" void kernel_launch(void* const* d_in, const int* in_sizes, int n_in,
                              void* d_out, int out_size, void* d_ws, size_t ws_size,
                              hipStream_t stream) {
    const float* x    = (const float*)d_in[0];
    const float* cosb = (const float*)d_in[1];
    const float* sinb = (const float*)d_in[2];
    const float* Wq   = (const float*)d_in[3];
    const float* bq   = (const float*)d_in[4];
    const float* Wk   = (const float*)d_in[5];
    const float* bk   = (const float*)d_in[6];
    const float* Wv   = (const float*)d_in[7];
    const float* bv   = (const float*)d_in[8];
    const float* Wo   = (const float*)d_in[9];
    float* out = (float*)d_out;

    // workspace (all bf16 as ushort):
    // xb[4096*2048] Wt[3072*2048] Wot[2048*2048] qb[4096*2048]
    // kb[4096*512] vb[4096*512] vtb[1024*2048] yb[4096*2048]  = 83.9 MB
    unsigned short* xb  = (unsigned short*)d_ws;
    unsigned short* Wt  = xb  + (size_t)MM * CC;
    unsigned short* Wot = Wt  + (size_t)3072 * 2048;
    unsigned short* qb  = Wot + (size_t)2048 * 2048;
    unsigned short* kb  = qb  + (size_t)MM * CC;
    unsigned short* vb  = kb  + (size_t)MM * (HKK * HD);
    unsigned short* vtb = vb  + (size_t)MM * (HKK * HD);
    unsigned short* ybf = vtb + (size_t)BB * HKK * HD * TT;

    cast_x_kernel<<<dim3((MM * CC) / 2048), 256, 0, stream>>>(x, xb);
    wtrans_kernel<<<dim3(32, 32, 4), 256, 0, stream>>>(Wq, Wk, Wv, Wo, Wt, Wot);
    qkv_gemm_mfma<<<dim3(3072 / 128, MM / 128), 256, 0, stream>>>(
        xb, Wt, bq, bk, bv, cosb, sinb, qb, kb, vb);
    vtrans_kernel<<<dim3(TT / 64, HD / 64, BB * HKK), 256, 0, stream>>>(vb, vtb);
    flash_mfma<<<dim3(BB * HH, TT / 128), 512, 0, stream>>>(qb, kb, vtb, ybf);
    out_gemm_mfma<<<dim3(CC / 128, MM / 128), 256, 0, stream>>>(ybf, Wot, out);
}